// Round 12
// baseline (192.923 us; speedup 1.0000x reference)
//
#include <hip/hip_runtime.h>
#include <hip/hip_bf16.h>

typedef unsigned short u16;
typedef unsigned int u32;
typedef __attribute__((ext_vector_type(4))) float f32x4;
typedef __attribute__((ext_vector_type(8))) short bf16x8;

#define TOKENS 4096
#define DMODEL 1024
#define NEXP 32
#define ESIZE 512

// round-to-nearest-even f32 -> bf16 bits
__device__ __forceinline__ u16 f2b(float f) {
  union { float f; u32 u; } v; v.f = f;
  u32 u = v.u;
  return (u16)((u + 0x7fffu + ((u >> 16) & 1u)) >> 16);
}

// packed f32x2 -> bf16x2
__device__ __forceinline__ u32 pk2(float a, float b) {
  union { __hip_bfloat162 h; u32 u; } v;
  v.h = __float22bfloat162_rn(make_float2(a, b));
  return v.u;
}

__device__ __forceinline__ float blo(u32 w) { union { u32 u; float f; } v; v.u = w << 16; return v.f; }
__device__ __forceinline__ float bhi(u32 w) { union { u32 u; float f; } v; v.u = w & 0xffff0000u; return v.f; }

// async global->LDS, 16B per lane; LDS dest = wave-uniform base + lane*16
typedef __attribute__((address_space(1))) const void as1_void;
typedef __attribute__((address_space(3))) void as3_void;
__device__ __forceinline__ void gl16(const void* g, void* l) {
  __builtin_amdgcn_global_load_lds((as1_void*)g, (as3_void*)l, 16, 0, 0);
}

// stride-72 swizzled LDS addr (shorts) for fallback reg-staged tiles
__device__ __forceinline__ int swz(int row, int kk) {
  return row * 72 + ((((kk >> 3) ^ (row >> 2)) & 7) << 3) + (kk & 7);
}

// ---------------- es transpose: esT4[dblk][e][j] = es[e][4*dblk+j] ----------------
__global__ __launch_bounds__(256) void k_esT(const float* __restrict__ es,
                                             float* __restrict__ esT4)
{
  int tid = threadIdx.x;
  int dblk = (blockIdx.x << 3) + (tid >> 5);
  int e = tid & 31;
  float4 v = *(const float4*)(es + (size_t)e * DMODEL + (dblk << 2));
  *((float4*)esT4 + (size_t)dblk * 32 + e) = v;
}

// ---- pipelined 4-tile transpose-convert: f32 [E][R][C] -> bf16 [E][C][R] ----
// Per tile: write regs->LDS, sync, ISSUE next tile's loads (latency hides under
// the transpose/store phase), process, sync.
__device__ __forceinline__ void tr_tiles4(const float* __restrict__ src,
                                          u16* __restrict__ dst, int R, int C,
                                          int cx, int cyBase, int e, int t,
                                          float* smemf)
{
  float (*tile)[68] = (float(*)[68])smemf;   // 64*68*4 = 17408 B
  int c0 = cx << 6;
  int rr = t >> 2, cb = (t & 3) << 4;
  int wr = t >> 2, wb = (t & 3) << 4;
  float4 r[4];
  {
    const float* sp = src + ((size_t)e * R + (cyBase << 6) + rr) * C + c0 + cb;
#pragma unroll
    for (int j = 0; j < 4; ++j) r[j] = *(const float4*)(sp + (j << 2));
  }
#pragma unroll 1
  for (int s = 0; s < 4; ++s) {
#pragma unroll
    for (int j = 0; j < 4; ++j) *(float4*)&tile[rr][cb + (j << 2)] = r[j];
    __syncthreads();
    if (s + 1 < 4) {
      const float* sp = src + ((size_t)e * R + ((cyBase + s + 1) << 6) + rr) * C + c0 + cb;
#pragma unroll
      for (int j = 0; j < 4; ++j) r[j] = *(const float4*)(sp + (j << 2));
    }
    int r0 = (cyBase + s) << 6;
    u32 q[8];
#pragma unroll
    for (int j = 0; j < 8; ++j)
      q[j] = pk2(tile[wb + (j << 1)][wr], tile[wb + (j << 1) + 1][wr]);
    u16* dp = dst + ((size_t)e * C + c0 + wr) * R + r0 + wb;
    *(uint4*)dp = make_uint4(q[0], q[1], q[2], q[3]);
    *(uint4*)(dp + 8) = make_uint4(q[4], q[5], q[6], q[7]);
    __syncthreads();
  }
}

// ---------------- mega1: route (0..511) ∥ keys-tr (512..1535) ∥ values-tr (1536..2559)
__global__ __launch_bounds__(256) void k_mega1(
    const float* __restrict__ x, const float* __restrict__ esT4,
    float* __restrict__ selval, u32* __restrict__ selpk,
    float* __restrict__ blockpart, u16* __restrict__ xb,
    const float* __restrict__ keys, const float* __restrict__ values,
    u16* __restrict__ kb, u16* __restrict__ vb)
{
  __shared__ __align__(16) float smem[4352];   // 17408 B union
  int bid = blockIdx.x;
  int tid = threadIdx.x;

  if (bid >= 1536) {                // values-tr: 16 cx x 2 grp x 32 e
    int i = bid - 1536;
    tr_tiles4(values, vb, ESIZE, DMODEL, i & 15, ((i >> 4) & 1) << 2, i >> 5, tid, smem);
    return;
  }
  if (bid >= 512) {                 // keys-tr: 8 cx x 4 grp x 32 e
    int i = bid - 512;
    tr_tiles4(keys, kb, DMODEL, ESIZE, i & 7, ((i >> 3) & 3) << 2, i >> 5, tid, smem);
    return;
  }

  // ---- routing: K-split across 4 waves, 8 tokens/block ----
  float (*part)[8][32] = (float(*)[8][32])smem;          // 4 KB
  float (*ps)[32] = (float(*)[32])(smem + 1024);         // 1 KB
  int w = tid >> 6, lane = tid & 63;
  int e = lane & 31, h = lane >> 5;
  int t0 = bid << 3;

  const float4* ev = (const float4*)esT4 + (size_t)((w << 6) + (h << 5)) * 32 + e;
  const float4* xv = (const float4*)x + ((size_t)t0 << 8) + (w << 6) + (h << 5);

  float acc[8];
#pragma unroll
  for (int tk = 0; tk < 8; ++tk) acc[tk] = 0.f;

#pragma unroll 2
  for (int i = 0; i < 32; ++i) {
    float4 b = ev[(size_t)i * 32];
#pragma unroll
    for (int tk = 0; tk < 8; ++tk) {
      float4 a = xv[(tk << 8) + i];
      acc[tk] += a.x * b.x + a.y * b.y + a.z * b.z + a.w * b.w;
    }
  }
#pragma unroll
  for (int tk = 0; tk < 8; ++tk) {
    float s = acc[tk] + __shfl_xor(acc[tk], 32);
    if (h == 0) part[w][tk][e] = s;
  }
  __syncthreads();

  int tk = tid >> 5, ge = tid & 31;
  {
    float r = part[0][tk][ge] + part[1][tk][ge] + part[2][tk][ge] + part[3][tk][ge];
    int t = t0 + tk;

    float m = r;
#pragma unroll
    for (int mk = 16; mk; mk >>= 1) m = fmaxf(m, __shfl_xor(m, mk));
    float sx = __expf(r - m);
#pragma unroll
    for (int mk = 16; mk; mk >>= 1) sx += __shfl_xor(sx, mk);
    ps[tk][ge] = __expf(r - (m + __logf(sx)));

    u32 packed = 0;
    float v = r;
#pragma unroll
    for (int it = 0; it < 4; ++it) {
      float bv = v; int bi = ge;
#pragma unroll
      for (int mk = 16; mk; mk >>= 1) {
        float ov = __shfl_xor(bv, mk); int oi = __shfl_xor(bi, mk);
        if (ov > bv || (ov == bv && oi < bi)) { bv = ov; bi = oi; }
      }
      packed |= (u32)bi << (8 * it);
      if (ge == it) selval[t * 4 + it] = 1.f / (1.f + __expf(-bv));
      if (ge == bi) v = -3.0e38f;
    }
    if (ge == 0) selpk[t] = packed;
  }
  __syncthreads();
  if (tid < 32) {
    float s = 0.f;
#pragma unroll
    for (int j = 0; j < 8; ++j) s += ps[j][tid];
    blockpart[bid * 32 + tid] = s;
  }

  // fused x -> bf16 for this block's 8 rows (coalesced)
  if (xb) {
    const float4* src = (const float4*)x + ((size_t)bid << 11);
    u16* dst = xb + ((size_t)bid << 13);
#pragma unroll
    for (int j = 0; j < 8; ++j) {
      int idx = (j << 8) + tid;
      float4 a = src[idx];
      *(uint2*)(dst + (idx << 2)) = make_uint2(pk2(a.x, a.y), pk2(a.z, a.w));
    }
  }
}

// ---------------- bucket build + entropy regularizer (merged, uniform barriers) ----
__global__ __launch_bounds__(1024) void k_cf(
    const u32* __restrict__ selpk, int* __restrict__ cnt, int* __restrict__ bucket,
    const float* __restrict__ blockpart, float* __restrict__ out_reg)
{
  __shared__ int cl[32];
  __shared__ float pf[32][33];
  int tid = threadIdx.x;
  if (tid < 32) cl[tid] = 0;
  __syncthreads();
  int ex[16], pos[16];
#pragma unroll
  for (int j = 0; j < 4; ++j) {
    int t = tid + (j << 10);
    u32 pk = selpk[t];
#pragma unroll
    for (int h = 0; h < 4; ++h) {
      int e = (pk >> (8 * h)) & 0xff;
      ex[j * 4 + h] = e;
      pos[j * 4 + h] = atomicAdd(&cl[e], 1);
    }
  }
#pragma unroll
  for (int j = 0; j < 4; ++j) {
    int t = tid + (j << 10);
#pragma unroll
    for (int h = 0; h < 4; ++h)
      bucket[ex[j * 4 + h] * TOKENS + pos[j * 4 + h]] = (t << 2) | h;
  }
  __syncthreads();
  if (tid < 32) cnt[tid] = cl[tid];

  // fin: colsum over 512 blockparts
  int e = tid & 31, c = tid >> 5;
  float s = 0.f;
  for (int b = c; b < 512; b += 32) s += blockpart[b * 32 + e];
  pf[c][e] = s;
  __syncthreads();
  if (tid < 32) {
    float S = 0.f;
#pragma unroll
    for (int i = 0; i < 32; ++i) S += pf[i][tid];
    float Pm = S * (1.0f / TOKENS);
    float rp = __logf(Pm) * Pm;
#pragma unroll
    for (int mk = 16; mk; mk >>= 1) rp += __shfl_xor(rp, mk);
    if (tid == 0) *out_reg = rp;
  }
}

// ======== fast GEMMs (round-9 proven): global_load_lds staging, XOR-granule swizzle,
// 2-deep counted-vmcnt pipeline ========
#define GEMM_MACROS                                                                          \
  int wm = (w >> 1) << 6, wn = (w & 1) << 6;                                                 \
  int w32 = w << 5;                                                                          \
  int lg16 = (((l & 7) ^ (l >> 3)) << 4);

#define STAGE(BUF, K0) do {                                                                  \
  _Pragma("unroll") for (int i_ = 0; i_ < 4; ++i_)                                           \
    gl16(gA[i_] + ((K0) << 1), (void*)&Ab[BUF][(((w << 2) + i_) << 9)]);                     \
  _Pragma("unroll") for (int i_ = 0; i_ < 4; ++i_)                                           \
    gl16(gB[i_] + ((K0) << 1), (void*)&Bb[BUF][(((w << 2) + i_) << 9)]);                     \
} while (0)

#define COMPUTE(CUR) do {                                                                    \
  _Pragma("unroll") for (int kh_ = 0; kh_ < 2; ++kh_) {                                      \
    bf16x8 af_[4], bf_[4];                                                                   \
    int gg_ = (kh_ << 2) + (l >> 4);                                                         \
    _Pragma("unroll") for (int mi_ = 0; mi_ < 4; ++mi_) {                                    \
      int row_ = wm + (mi_ << 4) + (l & 15);                                                 \
      af_[mi_] = *(const bf16x8*)&Ab[CUR][(row_ << 6) + ((gg_ ^ (row_ & 7)) << 3)];          \
    }                                                                                        \
    _Pragma("unroll") for (int ni_ = 0; ni_ < 4; ++ni_) {                                    \
      int row_ = wn + (ni_ << 4) + (l & 15);                                                 \
      bf_[ni_] = *(const bf16x8*)&Bb[CUR][(row_ << 6) + ((gg_ ^ (row_ & 7)) << 3)];          \
    }                                                                                        \
    _Pragma("unroll") for (int mi_ = 0; mi_ < 4; ++mi_)                                      \
      _Pragma("unroll") for (int ni_ = 0; ni_ < 4; ++ni_)                                    \
        acc[mi_][ni_] = __builtin_amdgcn_mfma_f32_16x16x32_bf16(af_[mi_], bf_[ni_],          \
                                                                acc[mi_][ni_], 0, 0, 0);     \
  }                                                                                          \
} while (0)

// counted-vmcnt K-loop over NT tiles of 64
#define KLOOP(NT) do {                                                                       \
  STAGE(0, 0);                                                                               \
  STAGE(1, 64);                                                                              \
  _Pragma("unroll 1")                                                                        \
  for (int t_ = 0; t_ < (NT); ++t_) {                                                        \
    int cur_ = t_ & 1;                                                                       \
    if (t_ + 1 < (NT)) { asm volatile("s_waitcnt vmcnt(8)" ::: "memory"); }                  \
    else               { asm volatile("s_waitcnt vmcnt(0)" ::: "memory"); }                  \
    asm volatile("s_barrier" ::: "memory");                                                  \
    COMPUTE(cur_);                                                                           \
    asm volatile("s_barrier" ::: "memory");                                                  \
    if (t_ + 2 < (NT)) STAGE(cur_, (t_ + 2) << 6);                                           \
  }                                                                                          \
} while (0)

// XCD-affine decode: bid = ((e>>3)*16 + sub)*8 + (e&7)
#define XCD_DECODE(SUB_NS_BITS)                                                              \
  int bid = blockIdx.x;                                                                      \
  int q_ = bid >> 3, sub_ = q_ & 15;                                                         \
  int e = ((q_ >> 4) << 3) | (bid & 7);                                                      \
  int ns = sub_ & ((1 << (SUB_NS_BITS)) - 1);                                                \
  int mz = sub_ >> (SUB_NS_BITS);

// ---------------- up-projection: scores[slot] = relu(xb[t] @ kb[e]^T) * gate ----------------
__global__ __launch_bounds__(256, 2) void k_up(
    const u16* __restrict__ xb, const u16* __restrict__ kb,
    const float* __restrict__ selval, const int* __restrict__ cnt,
    const int* __restrict__ bucket, const u16* __restrict__ zeros,
    u16* __restrict__ scores)
{
  XCD_DECODE(2);                       // 4 ns x 4 mz
  int ne = cnt[e];
  if ((mz << 7) >= ne) return;
  int nb0 = ns << 7;
  int tid = threadIdx.x, l = tid & 63, w = tid >> 6;

  __shared__ __align__(16) u16 Ab[2][8192];
  __shared__ __align__(16) u16 Bb[2][8192];
  __shared__ int slot_l[128];
  __shared__ float gate_l[128];

  GEMM_MACROS;

  const char* gB[4];
#pragma unroll
  for (int i = 0; i < 4; ++i) {
    int n = nb0 + w32 + (i << 3) + (l >> 3);
    gB[i] = (const char*)(kb + ((size_t)e * ESIZE + n) * DMODEL) + lg16;
  }

  for (int mt = mz; (mt << 7) < ne; mt += 4) {
    int row0 = mt << 7;
    int rem = ne - row0; if (rem > 128) rem = 128;
    __syncthreads();
    if (tid < 128) {
      int slot = -1; float g = 0.f;
      if (tid < rem) { slot = bucket[e * TOKENS + row0 + tid]; g = selval[slot]; }
      slot_l[tid] = slot; gate_l[tid] = g;
    }
    __syncthreads();

    const char* gA[4];
#pragma unroll
    for (int i = 0; i < 4; ++i) {
      int s = slot_l[w32 + (i << 3) + (l >> 3)];
      gA[i] = ((s >= 0) ? (const char*)(xb + (size_t)(s >> 2) * DMODEL)
                        : (const char*)zeros) + lg16;
    }

    f32x4 acc[4][4];
#pragma unroll
    for (int i = 0; i < 4; ++i)
#pragma unroll
      for (int j = 0; j < 4; ++j) acc[i][j] = (f32x4){0.f, 0.f, 0.f, 0.f};

    KLOOP(16);

#pragma unroll
    for (int mi = 0; mi < 4; ++mi) {
      int rbase = wm + (mi << 4) + ((l >> 4) << 2);
#pragma unroll
      for (int rr = 0; rr < 4; ++rr) {
        int r = rbase + rr;
        if (r < rem) {
          float g = gate_l[r];
          u16* so = scores + (size_t)slot_l[r] * ESIZE + nb0 + wn + (l & 15);
#pragma unroll
          for (int ni = 0; ni < 4; ++ni)
            so[ni << 4] = f2b(fmaxf(acc[mi][ni][rr], 0.f) * g);
        }
      }
    }
  }
}

// ---------------- down-projection: stage[slot] = scores[slot] @ vb[e]^T ----------------
__global__ __launch_bounds__(256, 2) void k_down(
    const u16* __restrict__ scores, const u16* __restrict__ vb,
    const int* __restrict__ cnt, const int* __restrict__ bucket,
    const u16* __restrict__ zeros, u16* __restrict__ stage)
{
  XCD_DECODE(3);                       // 8 ns x 2 mz
  int ne = cnt[e];
  if ((mz << 7) >= ne) return;
  int nb0 = ns << 7;
  int tid = threadIdx.x, l = tid & 63, w = tid >> 6;

  __shared__ __align__(16) u16 Ab[2][8192];
  __shared__ __align__(16) u16 Bb[2][8192];
  __shared__ int slot_l[128];

  GEMM_MACROS;

  const char* gB[4];
#pragma unroll
  for (int i = 0; i < 4; ++i) {
    int n = nb0 + w32 + (i << 3) + (l >> 3);
    gB[i] = (const char*)(vb + ((size_t)e * DMODEL + n) * ESIZE) + lg16;
  }

  for (int mt = mz; (mt << 7) < ne; mt += 2) {
    int row0 = mt << 7;
    int rem = ne - row0; if (rem > 128) rem = 128;
    __syncthreads();
    if (tid < 128) {
      int slot = -1;
      if (tid < rem) slot = bucket[e * TOKENS + row0 + tid];
      slot_l[tid] = slot;
    }
    __syncthreads();

    const char* gA[4];
#pragma unroll
    for (int i = 0; i < 4; ++i) {
      int s = slot_l[w32 + (i << 3) + (l >> 3)];
      gA[i] = ((s >= 0) ? (const char*)(scores + (size_t)s * ESIZE)
                        : (const char*)zeros) + lg16;
    }

    f32x4 acc[4][4];
#pragma unroll
    for (int i = 0; i < 4; ++i)
#pragma unroll
      for (int j = 0; j < 4; ++j) acc[i][j] = (f32x4){0.f, 0.f, 0.f, 0.f};

    KLOOP(8);

#pragma unroll
    for (int mi = 0; mi < 4; ++mi) {
      int rbase = wm + (mi << 4) + ((l >> 4) << 2);
#pragma unroll
      for (int rr = 0; rr < 4; ++rr) {
        int r = rbase + rr;
        if (r < rem) {
          u16* so = stage + (size_t)slot_l[r] * DMODEL + nb0 + wn + (l & 15);
#pragma unroll
          for (int ni = 0; ni < 4; ++ni)
            so[ni << 4] = f2b(acc[mi][ni][rr]);
        }
      }
    }
  }
}

// ---------------- final: out[t] = sum_h stage[t*4+h] ----------------
__global__ __launch_bounds__(256) void k_final(const u16* __restrict__ stage,
                                               float* __restrict__ out)
{
  int tid = threadIdx.x;
  int t = (blockIdx.x << 1) + (tid >> 7);
  int d0 = (tid & 127) << 3;
  const u16* r0 = stage + ((size_t)t << 12) + d0;
  uint4 a0 = *(const uint4*)(r0);
  uint4 a1 = *(const uint4*)(r0 + 1024);
  uint4 a2 = *(const uint4*)(r0 + 2048);
  uint4 a3 = *(const uint4*)(r0 + 3072);
  float4 lo4, hi4;
  lo4.x = blo(a0.x) + blo(a1.x) + blo(a2.x) + blo(a3.x);
  lo4.y = bhi(a0.x) + bhi(a1.x) + bhi(a2.x) + bhi(a3.x);
  lo4.z = blo(a0.y) + blo(a1.y) + blo(a2.y) + blo(a3.y);
  lo4.w = bhi(a0.y) + bhi(a1.y) + bhi(a2.y) + bhi(a3.y);
  hi4.x = blo(a0.z) + blo(a1.z) + blo(a2.z) + blo(a3.z);
  hi4.y = bhi(a0.z) + bhi(a1.z) + bhi(a2.z) + bhi(a3.z);
  hi4.z = blo(a0.w) + blo(a1.w) + blo(a2.w) + blo(a3.w);
  hi4.w = bhi(a0.w) + bhi(a1.w) + bhi(a2.w) + bhi(a3.w);
  float* o = out + (size_t)t * DMODEL + d0;
  *(float4*)o = lo4;
  *(float4*)(o + 4) = hi4;
}

// ================= fallback (reg-staged) kernels, used if ws too small =================
__global__ __launch_bounds__(256, 2) void k_up_rs(
    const float* __restrict__ x, const float* __restrict__ keys,
    const float* __restrict__ selval, const int* __restrict__ cnt,
    const int* __restrict__ bucket, u16* __restrict__ scores)
{
  int bid = blockIdx.x;
  int pair = bid & 127, mz = bid >> 7;
  int e = pair >> 2, ns = pair & 3;
  int ne = cnt[e];
  if ((mz << 7) >= ne) return;
  int nb0 = ns << 7;
  int tid = threadIdx.x;

  __shared__ __align__(16) u16 Abuf[2][128 * 72];
  __shared__ __align__(16) u16 Bbuf[2][128 * 72];
  __shared__ int slot_l[128];
  __shared__ float gate_l[128];

  const float* Kb = keys + (size_t)e * (DMODEL * ESIZE) + nb0;
  int arow = tid >> 1, ac0 = (tid & 1) << 5;
  int bn = tid & 31, bk0 = (tid >> 5) << 3;
  int lane = tid & 63, w = tid >> 6;
  int wm = (w >> 1) << 6, wn = (w & 1) << 6;

  for (int mt = mz; (mt << 7) < ne; mt += 4) {
    int row0 = mt << 7;
    int rem = ne - row0; if (rem > 128) rem = 128;
    __syncthreads();
    if (tid < 128) {
      int slot = -1; float g = 0.f;
      if (tid < rem) { slot = bucket[e * TOKENS + row0 + tid]; g = selval[slot]; }
      slot_l[tid] = slot; gate_l[tid] = g;
    }
    __syncthreads();

    int aslot = slot_l[arow];
    const float* xr = (aslot >= 0) ? (x + (size_t)(aslot >> 2) * DMODEL + ac0) : nullptr;
    const float* bp = Kb + (size_t)bk0 * ESIZE + (bn << 2);

    f32x4 acc[4][4];
#pragma unroll
    for (int i = 0; i < 4; ++i)
#pragma unroll
      for (int j = 0; j < 4; ++j) acc[i][j] = (f32x4){0.f, 0.f, 0.f, 0.f};

    float4 ar[8], br[8];
#define LOADA_UP(K) do { if (xr) { const float4* p_ = (const float4*)(xr + (K)); \
    _Pragma("unroll") for (int i_ = 0; i_ < 8; ++i_) ar[i_] = p_[i_]; } \
    else { _Pragma("unroll") for (int i_ = 0; i_ < 8; ++i_) ar[i_] = make_float4(0.f,0.f,0.f,0.f); } } while (0)
#define LOADB_RS(K, LDB) do { const float* q_ = bp + (size_t)(K) * (LDB); \
    _Pragma("unroll") for (int r_ = 0; r_ < 8; ++r_) br[r_] = *(const float4*)(q_ + (size_t)r_ * (LDB)); } while (0)
#define CVTWR_A(NB) do { _Pragma("unroll") for (int g_ = 0; g_ < 4; ++g_) { \
    u32 q0_ = pk2(ar[2*g_].x, ar[2*g_].y),   q1_ = pk2(ar[2*g_].z, ar[2*g_].w); \
    u32 q2_ = pk2(ar[2*g_+1].x, ar[2*g_+1].y), q3_ = pk2(ar[2*g_+1].z, ar[2*g_+1].w); \
    *(uint4*)&Abuf[NB][swz(arow, ac0 + 8*g_)] = make_uint4(q0_,q1_,q2_,q3_); } } while (0)
#define CVTWR_B(NB) do { \
    { u32 q0_=pk2(br[0].x,br[1].x),q1_=pk2(br[2].x,br[3].x),q2_=pk2(br[4].x,br[5].x),q3_=pk2(br[6].x,br[7].x); \
      *(uint4*)&Bbuf[NB][swz((bn<<2)+0, bk0)] = make_uint4(q0_,q1_,q2_,q3_); } \
    { u32 q0_=pk2(br[0].y,br[1].y),q1_=pk2(br[2].y,br[3].y),q2_=pk2(br[4].y,br[5].y),q3_=pk2(br[6].y,br[7].y); \
      *(uint4*)&Bbuf[NB][swz((bn<<2)+1, bk0)] = make_uint4(q0_,q1_,q2_,q3_); } \
    { u32 q0_=pk2(br[0].z,br[1].z),q1_=pk2(br[2].z,br[3].z),q2_=pk2(br[4].z,br[5].z),q3_=pk2(br[6].z,br[7].z); \
      *(uint4*)&Bbuf[NB][swz((bn<<2)+2, bk0)] = make_uint4(q0_,q1_,q2_,q3_); } \
    { u32 q0_=pk2(br[0].w,br[1].w),q1_=pk2(br[2].w,br[3].w),q2_=pk2(br[4].w,br[5].w),q3_=pk2(br[6].w,br[7].w); \
      *(uint4*)&Bbuf[NB][swz((bn<<2)+3, bk0)] = make_uint4(q0_,q1_,q2_,q3_); } } while (0)
#define MFMA_RS(CUR) do { _Pragma("unroll") for (int kh_ = 0; kh_ < 2; ++kh_) { \
    int kk_ = (kh_ << 5) | ((lane >> 4) << 3); \
    bf16x8 af_[4], bf_[4]; \
    _Pragma("unroll") for (int mi_ = 0; mi_ < 4; ++mi_) \
      af_[mi_] = *(const bf16x8*)&Abuf[CUR][swz(wm + (mi_ << 4) + (lane & 15), kk_)]; \
    _Pragma("unroll") for (int ni_ = 0; ni_ < 4; ++ni_) \
      bf_[ni_] = *(const bf16x8*)&Bbuf[CUR][swz(wn + (ni_ << 4) + (lane & 15), kk_)]; \
    _Pragma("unroll") for (int mi_ = 0; mi_ < 4; ++mi_) \
      _Pragma("unroll") for (int ni_ = 0; ni_ < 4; ++ni_) \
        acc[mi_][ni_] = __builtin_amdgcn_mfma_f32_16x16x32_bf16(af_[mi_], bf_[ni_], acc[mi_][ni_], 0, 0, 0); \
  } } while (0)

    LOADA_UP(0); LOADB_RS(0, ESIZE);
    CVTWR_A(0); CVTWR_B(0);
    __syncthreads();
    int cur = 0;
    for (int k0 = 0; k0 < DMODEL; k0 += 64) {
      bool late = (k0 + 64 >= DMODEL);
      if (!late) { LOADA_UP(k0 + 64); LOADB_RS(k0 + 64, ESIZE); }
      MFMA_RS(cur);
      if (!late) { CVTWR_A(cur ^ 1); CVTWR_B(cur ^ 1); }
      __syncthreads();
      cur ^= 1;
    }

#pragma unroll
    for (int mi = 0; mi < 4; ++mi) {
      int rbase = wm + (mi << 4) + ((lane >> 4) << 2);
#pragma unroll
      for (int rr = 0; rr < 4; ++rr) {
        int r = rbase + rr;
        if (r < rem) {
          float g = gate_l[r];
          u16* so = scores + (size_t)slot_l[r] * ESIZE + nb0 + wn + (lane & 15);
#pragma unroll
          for (int ni = 0; ni < 4; ++ni)
            so[ni << 4] = f2b(fmaxf(acc[mi][ni][rr], 0.f) * g);
        }
      }
    }
#undef LOADA_UP
#undef LOADB_RS
#undef CVTWR_A
#undef CVTWR_B
#undef MFMA_RS
  }
}

__global__ __launch_bounds__(256, 2) void k_down_rs(
    const u16* __restrict__ scores, const float* __restrict__ values,
    const int* __restrict__ cnt, const int* __restrict__ bucket,
    u16* __restrict__ stage, float* __restrict__ out)
{
  int bid = blockIdx.x;
  int pair = bid & 255, mz = bid >> 8;
  int e = pair >> 3, ns = pair & 7;
  int ne = cnt[e];
  if ((mz << 7) >= ne) return;
  int nb0 = ns << 7;
  int tid = threadIdx.x;

  __shared__ __align__(16) u16 Abuf[2][128 * 72];
  __shared__ __align__(16) u16 Bbuf[2][128 * 72];
  __shared__ int slot_l[128];

  const float* Vb = values + (size_t)e * (ESIZE * DMODEL) + nb0;
  int arow = tid >> 1, ac0 = (tid & 1) << 5;
  int bn = tid & 31, bk0 = (tid >> 5) << 3;
  int lane = tid & 63, w = tid >> 6;
  int wm = (w >> 1) << 6, wn = (w & 1) << 6;

  for (int mt = mz; (mt << 7) < ne; mt += 2) {
    int row0 = mt << 7;
    int rem = ne - row0; if (rem > 128) rem = 128;
    __syncthreads();
    if (tid < 128) {
      int slot = -1;
      if (tid < rem) slot = bucket[e * TOKENS + row0 + tid];
      slot_l[tid] = slot;
    }
    __syncthreads();

    int aslot = slot_l[arow];
    const u16* sr = (aslot >= 0) ? (scores + (size_t)aslot * ESIZE + ac0) : nullptr;
    const float* bp = Vb + (size_t)bk0 * DMODEL + (bn << 2);

    f32x4 acc[4][4];
#pragma unroll
    for (int i = 0; i < 4; ++i)
#pragma unroll
      for (int j = 0; j < 4; ++j) acc[i][j] = (f32x4){0.f, 0.f, 0.f, 0.f};

    uint4 a4[4]; float4 br[8];
#define LOADA_DN(K) do { if (sr) { const uint4* p_ = (const uint4*)(sr + (K)); \
    _Pragma("unroll") for (int i_ = 0; i_ < 4; ++i_) a4[i_] = p_[i_]; } \
    else { _Pragma("unroll") for (int i_ = 0; i_ < 4; ++i_) a4[i_] = make_uint4(0,0,0,0); } } while (0)
#define LOADB_RS(K, LDB) do { const float* q_ = bp + (size_t)(K) * (LDB); \
    _Pragma("unroll") for (int r_ = 0; r_ < 8; ++r_) br[r_] = *(const float4*)(q_ + (size_t)r_ * (LDB)); } while (0)
#define WR_A(NB) do { _Pragma("unroll") for (int g_ = 0; g_ < 4; ++g_) \
    *(uint4*)&Abuf[NB][swz(arow, ac0 + 8*g_)] = a4[g_]; } while (0)
#define CVTWR_B(NB) do { \
    { u32 q0_=pk2(br[0].x,br[1].x),q1_=pk2(br[2].x,br[3].x),q2_=pk2(br[4].x,br[5].x),q3_=pk2(br[6].x,br[7].x); \
      *(uint4*)&Bbuf[NB][swz((bn<<2)+0, bk0)] = make_uint4(q0_,q1_,q2_,q3_); } \
    { u32 q0_=pk2(br[0].y,br[1].y),q1_=pk2(br[2].y,br[3].y),q2_=pk2(br[4].y,br[5].y),q3_=pk2(br[6].y,br[7].y); \
      *(uint4*)&Bbuf[NB][swz((bn<<2)+1, bk0)] = make_uint4(q0_,q1_,q2_,q3_); } \
    { u32 q0_=pk2(br[0].z,br[1].z),q1_=pk2(br[2].z,br[3].z),q2_=pk2(br[4].z,br[5].z),q3_=pk2(br[6].z,br[7].z); \
      *(uint4*)&Bbuf[NB][swz((bn<<2)+2, bk0)] = make_uint4(q0_,q1_,q2_,q3_); } \
    { u32 q0_=pk2(br[0].w,br[1].w),q1_=pk2(br[2].w,br[3].w),q2_=pk2(br[4].w,br[5].w),q3_=pk2(br[6].w,br[7].w); \
      *(uint4*)&Bbuf[NB][swz((bn<<2)+3, bk0)] = make_uint4(q0_,q1_,q2_,q3_); } } while (0)
#define MFMA_RS(CUR) do { _Pragma("unroll") for (int kh_ = 0; kh_ < 2; ++kh_) { \
    int kk_ = (kh_ << 5) | ((lane >> 4) << 3); \
    bf16x8 af_[4], bf_[4]; \
    _Pragma("unroll") for (int mi_ = 0; mi_ < 4; ++mi_) \
      af_[mi_] = *(const bf16x8*)&Abuf[CUR][swz(wm + (mi_ << 4) + (lane & 15), kk_)]; \
    _Pragma("unroll") for (int ni_ = 0; ni_ < 4; ++ni_) \
      bf_[ni_] = *(const bf16x8*)&Bbuf[CUR][swz(wn + (ni_ << 4) + (lane & 15), kk_)]; \
    _Pragma("unroll") for (int mi_ = 0; mi_ < 4; ++mi_) \
      _Pragma("unroll") for (int ni_ = 0; ni_ < 4; ++ni_) \
        acc[mi_][ni_] = __builtin_amdgcn_mfma_f32_16x16x32_bf16(af_[mi_], bf_[ni_], acc[mi_][ni_], 0, 0, 0); \
  } } while (0)

    LOADA_DN(0); LOADB_RS(0, DMODEL);
    WR_A(0); CVTWR_B(0);
    __syncthreads();
    int cur = 0;
    for (int k0 = 0; k0 < ESIZE; k0 += 64) {
      bool late = (k0 + 64 >= ESIZE);
      if (!late) { LOADA_DN(k0 + 64); LOADB_RS(k0 + 64, DMODEL); }
      MFMA_RS(cur);
      if (!late) { WR_A(cur ^ 1); CVTWR_B(cur ^ 1); }
      __syncthreads();
      cur ^= 1;
    }

#pragma unroll
    for (int mi = 0; mi < 4; ++mi) {
      int rbase = wm + (mi << 4) + ((lane >> 4) << 2);
#pragma unroll
      for (int rr = 0; rr < 4; ++rr) {
        int r = rbase + rr;
        if (r < rem) {
          if (stage) {
            u16* so = stage + (size_t)slot_l[r] * DMODEL + nb0 + wn + (lane & 15);
#pragma unroll
            for (int ni = 0; ni < 4; ++ni)
              so[ni << 4] = f2b(acc[mi][ni][rr]);
          } else {
            int t = slot_l[r] >> 2;
            float* oo = out + (size_t)t * DMODEL + nb0 + wn + (lane & 15);
#pragma unroll
            for (int ni = 0; ni < 4; ++ni)
              atomicAdd(&oo[ni << 4], acc[mi][ni][rr]);
          }
        }
      }
    }
#undef LOADA_DN
#undef LOADB_RS
#undef WR_A
#undef CVTWR_B
#undef MFMA_RS
  }
}

extern "C" void kernel_launch(void* const* d_in, const int* in_sizes, int n_in,
                              void* d_out, int out_size, void* d_ws, size_t ws_size,
                              hipStream_t stream) {
  (void)in_sizes; (void)n_in;
  const float* x      = (const float*)d_in[0];
  const float* keys   = (const float*)d_in[1];
  const float* values = (const float*)d_in[2];
  const float* es     = (const float*)d_in[3];
  float* out = (float*)d_out;

  char* W = (char*)d_ws;
  int*   cnt       = (int*)W;                        // 128 B
  u16*   zeros     = (u16*)(W + 4 * 1024);           // 4 KB
  u32*   selpk     = (u32*)(W + 16 * 1024);          // 16 KB
  float* selval    = (float*)(W + 64 * 1024);        // 64 KB
  float* blockpart = (float*)(W + 128 * 1024);       // 64 KB f32 [512][32]
  int*   bucket    = (int*)(W + 512 * 1024);         // 512 KB
  float* esT4      = (float*)(W + 1280 * 1024);      // 128 KB f32 [256][32][4]

  bool big = ws_size >= (90ull << 20);

  k_esT<<<32, 256, 0, stream>>>(es, esT4);

  if (big) {
    u16* xb     = (u16*)(W + 2ull * 1024 * 1024);    // 8 MB  bf16 [4096][1024]
    u16* scores = (u16*)(W + 10ull * 1024 * 1024);   // 16 MB bf16 [16384][512]
    u16* kb     = (u16*)(W + 26ull * 1024 * 1024);   // 32 MB bf16 [32][512][1024]
    u16* vb     = (u16*)(W + 58ull * 1024 * 1024);   // 32 MB bf16 [32][1024][512]
    u16* stage  = kb;  // aliases kb: kb dead after k_up, stage written by k_down
    hipMemsetAsync(zeros, 0, 4096, stream);
    // route (512, first) ∥ keys-tr (1024 x 4 tiles) ∥ values-tr (1024 x 4 tiles)
    k_mega1<<<2560, 256, 0, stream>>>(
        x, esT4, selval, selpk, blockpart, xb, keys, values, kb, vb);
    k_cf<<<1, 1024, 0, stream>>>(selpk, cnt, bucket, blockpart,
                                 out + (size_t)out_size - 1);
    k_up<<<512, 256, 0, stream>>>(xb, kb, selval, cnt, bucket, zeros, scores);
    k_down<<<512, 256, 0, stream>>>(scores, vb, cnt, bucket, zeros, stage);
    k_final<<<TOKENS / 2, 256, 0, stream>>>(stage, out);
  } else {
    u16* scores = (u16*)(W + 2ull * 1024 * 1024);
    bool big50 = ws_size >= (50ull << 20);
    u16* stage = big50 ? (u16*)(W + 18ull * 1024 * 1024) : nullptr;
    if (!big50)
      hipMemsetAsync(d_out, 0, (size_t)out_size * sizeof(float), stream);
    k_mega1<<<512, 256, 0, stream>>>(
        x, esT4, selval, selpk, blockpart, nullptr, nullptr, nullptr, nullptr, nullptr);
    k_cf<<<1, 1024, 0, stream>>>(selpk, cnt, bucket, blockpart,
                                 out + (size_t)out_size - 1);
    k_up_rs<<<512, 256, 0, stream>>>(x, keys, selval, cnt, bucket, scores);
    k_down_rs<<<512, 256, 0, stream>>>(scores, values, cnt, bucket, stage, out);
    if (big50)
      k_final<<<TOKENS / 2, 256, 0, stream>>>(stage, out);
  }
}

// Round 13
// 177.565 us; speedup vs baseline: 1.0865x; 1.0865x over previous
//
#include <hip/hip_runtime.h>
#include <hip/hip_bf16.h>

typedef unsigned short u16;
typedef unsigned int u32;
typedef __attribute__((ext_vector_type(4))) float f32x4;
typedef __attribute__((ext_vector_type(8))) short bf16x8;

#define TOKENS 4096
#define DMODEL 1024
#define NEXP 32
#define ESIZE 512

// round-to-nearest-even f32 -> bf16 bits
__device__ __forceinline__ u16 f2b(float f) {
  union { float f; u32 u; } v; v.f = f;
  u32 u = v.u;
  return (u16)((u + 0x7fffu + ((u >> 16) & 1u)) >> 16);
}

// packed f32x2 -> bf16x2
__device__ __forceinline__ u32 pk2(float a, float b) {
  union { __hip_bfloat162 h; u32 u; } v;
  v.h = __float22bfloat162_rn(make_float2(a, b));
  return v.u;
}

__device__ __forceinline__ float blo(u32 w) { union { u32 u; float f; } v; v.u = w << 16; return v.f; }
__device__ __forceinline__ float bhi(u32 w) { union { u32 u; float f; } v; v.u = w & 0xffff0000u; return v.f; }

// async global->LDS, 16B per lane; LDS dest = wave-uniform base + lane*16
typedef __attribute__((address_space(1))) const void as1_void;
typedef __attribute__((address_space(3))) void as3_void;
__device__ __forceinline__ void gl16(const void* g, void* l) {
  __builtin_amdgcn_global_load_lds((as1_void*)g, (as3_void*)l, 16, 0, 0);
}

// stride-72 swizzled LDS addr (shorts) for fallback reg-staged tiles
__device__ __forceinline__ int swz(int row, int kk) {
  return row * 72 + ((((kk >> 3) ^ (row >> 2)) & 7) << 3) + (kk & 7);
}

// ---------------- es transpose: esT4[dblk][e][j] = es[e][4*dblk+j] ----------------
__global__ __launch_bounds__(256) void k_esT(const float* __restrict__ es,
                                             float* __restrict__ esT4)
{
  int tid = threadIdx.x;
  int dblk = (blockIdx.x << 3) + (tid >> 5);
  int e = tid & 31;
  float4 v = *(const float4*)(es + (size_t)e * DMODEL + (dblk << 2));
  *((float4*)esT4 + (size_t)dblk * 32 + e) = v;
}

// ---- 2-tile transpose-convert across experts e and e+16 (same cx,cy):
// keeps round-11's cross-block cy write concurrency (L2 line merging) while
// tile B's HBM load latency hides under tile A's LDS+transpose+store phase.
__device__ __forceinline__ void tr_tiles2(const float* __restrict__ src,
                                          u16* __restrict__ dst, int R, int C,
                                          int cx, int cy, int e, int t, float* smemf)
{
  float (*tileA)[68] = (float(*)[68])smemf;            // 17408 B
  float (*tileB)[68] = (float(*)[68])(smemf + 4352);   // 17408 B
  int r0 = cy << 6, c0 = cx << 6;
  int rr = t >> 2, cb = (t & 3) << 4;
  const float* spA = src + ((size_t)e * R + r0 + rr) * C + c0 + cb;
  const float* spB = spA + (size_t)16 * R * C;
  float4 ra[4], rb[4];
#pragma unroll
  for (int j = 0; j < 4; ++j) ra[j] = *(const float4*)(spA + (j << 2));
#pragma unroll
  for (int j = 0; j < 4; ++j) rb[j] = *(const float4*)(spB + (j << 2));
#pragma unroll
  for (int j = 0; j < 4; ++j) *(float4*)&tileA[rr][cb + (j << 2)] = ra[j];
  __syncthreads();
  int wr = t >> 2, wb = (t & 3) << 4;
  u32 q[8];
#pragma unroll
  for (int j = 0; j < 8; ++j)
    q[j] = pk2(tileA[wb + (j << 1)][wr], tileA[wb + (j << 1) + 1][wr]);
  {
    u16* dp = dst + ((size_t)e * C + c0 + wr) * R + r0 + wb;
    *(uint4*)dp = make_uint4(q[0], q[1], q[2], q[3]);
    *(uint4*)(dp + 8) = make_uint4(q[4], q[5], q[6], q[7]);
  }
#pragma unroll
  for (int j = 0; j < 4; ++j) *(float4*)&tileB[rr][cb + (j << 2)] = rb[j];
  __syncthreads();
#pragma unroll
  for (int j = 0; j < 8; ++j)
    q[j] = pk2(tileB[wb + (j << 1)][wr], tileB[wb + (j << 1) + 1][wr]);
  {
    u16* dp = dst + ((size_t)(e + 16) * C + c0 + wr) * R + r0 + wb;
    *(uint4*)dp = make_uint4(q[0], q[1], q[2], q[3]);
    *(uint4*)(dp + 8) = make_uint4(q[4], q[5], q[6], q[7]);
  }
}

// ---------------- mega1: route (0..511) ∥ keys-tr pairs (512..2559) ∥ values-tr pairs
__global__ __launch_bounds__(256) void k_mega1(
    const float* __restrict__ x, const float* __restrict__ esT4,
    float* __restrict__ selval, u32* __restrict__ selpk,
    float* __restrict__ blockpart, u16* __restrict__ xb,
    const float* __restrict__ keys, const float* __restrict__ values,
    u16* __restrict__ kb, u16* __restrict__ vb)
{
  __shared__ __align__(16) float smem[8704];   // 34816 B union (2 tiles)
  int bid = blockIdx.x;
  int tid = threadIdx.x;

  if (bid >= 2560) {                // values-tr: 16 cx x 8 cy x 16 e-pairs
    int i = bid - 2560;
    tr_tiles2(values, vb, ESIZE, DMODEL, i & 15, (i >> 4) & 7, i >> 7, tid, smem);
    return;
  }
  if (bid >= 512) {                 // keys-tr: 8 cx x 16 cy x 16 e-pairs
    int i = bid - 512;
    tr_tiles2(keys, kb, DMODEL, ESIZE, i & 7, (i >> 3) & 15, i >> 7, tid, smem);
    return;
  }

  // ---- routing: K-split across 4 waves, 8 tokens/block ----
  float (*part)[8][32] = (float(*)[8][32])smem;          // 4 KB
  float (*ps)[32] = (float(*)[32])(smem + 1024);         // 1 KB
  int w = tid >> 6, lane = tid & 63;
  int e = lane & 31, h = lane >> 5;
  int t0 = bid << 3;

  const float4* ev = (const float4*)esT4 + (size_t)((w << 6) + (h << 5)) * 32 + e;
  const float4* xv = (const float4*)x + ((size_t)t0 << 8) + (w << 6) + (h << 5);

  float acc[8];
#pragma unroll
  for (int tk = 0; tk < 8; ++tk) acc[tk] = 0.f;

#pragma unroll 2
  for (int i = 0; i < 32; ++i) {
    float4 b = ev[(size_t)i * 32];
#pragma unroll
    for (int tk = 0; tk < 8; ++tk) {
      float4 a = xv[(tk << 8) + i];
      acc[tk] += a.x * b.x + a.y * b.y + a.z * b.z + a.w * b.w;
    }
  }
#pragma unroll
  for (int tk = 0; tk < 8; ++tk) {
    float s = acc[tk] + __shfl_xor(acc[tk], 32);
    if (h == 0) part[w][tk][e] = s;
  }
  __syncthreads();

  int tk = tid >> 5, ge = tid & 31;
  {
    float r = part[0][tk][ge] + part[1][tk][ge] + part[2][tk][ge] + part[3][tk][ge];
    int t = t0 + tk;

    float m = r;
#pragma unroll
    for (int mk = 16; mk; mk >>= 1) m = fmaxf(m, __shfl_xor(m, mk));
    float sx = __expf(r - m);
#pragma unroll
    for (int mk = 16; mk; mk >>= 1) sx += __shfl_xor(sx, mk);
    ps[tk][ge] = __expf(r - (m + __logf(sx)));

    u32 packed = 0;
    float v = r;
#pragma unroll
    for (int it = 0; it < 4; ++it) {
      float bv = v; int bi = ge;
#pragma unroll
      for (int mk = 16; mk; mk >>= 1) {
        float ov = __shfl_xor(bv, mk); int oi = __shfl_xor(bi, mk);
        if (ov > bv || (ov == bv && oi < bi)) { bv = ov; bi = oi; }
      }
      packed |= (u32)bi << (8 * it);
      if (ge == it) selval[t * 4 + it] = 1.f / (1.f + __expf(-bv));
      if (ge == bi) v = -3.0e38f;
    }
    if (ge == 0) selpk[t] = packed;
  }
  __syncthreads();
  if (tid < 32) {
    float s = 0.f;
#pragma unroll
    for (int j = 0; j < 8; ++j) s += ps[j][tid];
    blockpart[bid * 32 + tid] = s;
  }

  // fused x -> bf16 for this block's 8 rows (coalesced)
  if (xb) {
    const float4* src = (const float4*)x + ((size_t)bid << 11);
    u16* dst = xb + ((size_t)bid << 13);
#pragma unroll
    for (int j = 0; j < 8; ++j) {
      int idx = (j << 8) + tid;
      float4 a = src[idx];
      *(uint2*)(dst + (idx << 2)) = make_uint2(pk2(a.x, a.y), pk2(a.z, a.w));
    }
  }
}

// ---------------- bucket build + entropy regularizer (merged, uniform barriers) ----
__global__ __launch_bounds__(1024) void k_cf(
    const u32* __restrict__ selpk, int* __restrict__ cnt, int* __restrict__ bucket,
    const float* __restrict__ blockpart, float* __restrict__ out_reg)
{
  __shared__ int cl[32];
  __shared__ float pf[32][33];
  int tid = threadIdx.x;
  if (tid < 32) cl[tid] = 0;
  __syncthreads();
  int ex[16], pos[16];
#pragma unroll
  for (int j = 0; j < 4; ++j) {
    int t = tid + (j << 10);
    u32 pk = selpk[t];
#pragma unroll
    for (int h = 0; h < 4; ++h) {
      int e = (pk >> (8 * h)) & 0xff;
      ex[j * 4 + h] = e;
      pos[j * 4 + h] = atomicAdd(&cl[e], 1);
    }
  }
#pragma unroll
  for (int j = 0; j < 4; ++j) {
    int t = tid + (j << 10);
#pragma unroll
    for (int h = 0; h < 4; ++h)
      bucket[ex[j * 4 + h] * TOKENS + pos[j * 4 + h]] = (t << 2) | h;
  }
  __syncthreads();
  if (tid < 32) cnt[tid] = cl[tid];

  // fin: colsum over 512 blockparts
  int e = tid & 31, c = tid >> 5;
  float s = 0.f;
  for (int b = c; b < 512; b += 32) s += blockpart[b * 32 + e];
  pf[c][e] = s;
  __syncthreads();
  if (tid < 32) {
    float S = 0.f;
#pragma unroll
    for (int i = 0; i < 32; ++i) S += pf[i][tid];
    float Pm = S * (1.0f / TOKENS);
    float rp = __logf(Pm) * Pm;
#pragma unroll
    for (int mk = 16; mk; mk >>= 1) rp += __shfl_xor(rp, mk);
    if (tid == 0) *out_reg = rp;
  }
}

// ======== fast GEMMs (round-9 proven): global_load_lds staging, XOR-granule swizzle,
// 2-deep counted-vmcnt pipeline ========
#define GEMM_MACROS                                                                          \
  int wm = (w >> 1) << 6, wn = (w & 1) << 6;                                                 \
  int w32 = w << 5;                                                                          \
  int lg16 = (((l & 7) ^ (l >> 3)) << 4);

#define STAGE(BUF, K0) do {                                                                  \
  _Pragma("unroll") for (int i_ = 0; i_ < 4; ++i_)                                           \
    gl16(gA[i_] + ((K0) << 1), (void*)&Ab[BUF][(((w << 2) + i_) << 9)]);                     \
  _Pragma("unroll") for (int i_ = 0; i_ < 4; ++i_)                                           \
    gl16(gB[i_] + ((K0) << 1), (void*)&Bb[BUF][(((w << 2) + i_) << 9)]);                     \
} while (0)

#define COMPUTE(CUR) do {                                                                    \
  _Pragma("unroll") for (int kh_ = 0; kh_ < 2; ++kh_) {                                      \
    bf16x8 af_[4], bf_[4];                                                                   \
    int gg_ = (kh_ << 2) + (l >> 4);                                                         \
    _Pragma("unroll") for (int mi_ = 0; mi_ < 4; ++mi_) {                                    \
      int row_ = wm + (mi_ << 4) + (l & 15);                                                 \
      af_[mi_] = *(const bf16x8*)&Ab[CUR][(row_ << 6) + ((gg_ ^ (row_ & 7)) << 3)];          \
    }                                                                                        \
    _Pragma("unroll") for (int ni_ = 0; ni_ < 4; ++ni_) {                                    \
      int row_ = wn + (ni_ << 4) + (l & 15);                                                 \
      bf_[ni_] = *(const bf16x8*)&Bb[CUR][(row_ << 6) + ((gg_ ^ (row_ & 7)) << 3)];          \
    }                                                                                        \
    _Pragma("unroll") for (int mi_ = 0; mi_ < 4; ++mi_)                                      \
      _Pragma("unroll") for (int ni_ = 0; ni_ < 4; ++ni_)                                    \
        acc[mi_][ni_] = __builtin_amdgcn_mfma_f32_16x16x32_bf16(af_[mi_], bf_[ni_],          \
                                                                acc[mi_][ni_], 0, 0, 0);     \
  }                                                                                          \
} while (0)

// counted-vmcnt K-loop over NT tiles of 64
#define KLOOP(NT) do {                                                                       \
  STAGE(0, 0);                                                                               \
  STAGE(1, 64);                                                                              \
  _Pragma("unroll 1")                                                                        \
  for (int t_ = 0; t_ < (NT); ++t_) {                                                        \
    int cur_ = t_ & 1;                                                                       \
    if (t_ + 1 < (NT)) { asm volatile("s_waitcnt vmcnt(8)" ::: "memory"); }                  \
    else               { asm volatile("s_waitcnt vmcnt(0)" ::: "memory"); }                  \
    asm volatile("s_barrier" ::: "memory");                                                  \
    COMPUTE(cur_);                                                                           \
    asm volatile("s_barrier" ::: "memory");                                                  \
    if (t_ + 2 < (NT)) STAGE(cur_, (t_ + 2) << 6);                                           \
  }                                                                                          \
} while (0)

// XCD-affine decode: bid = ((e>>3)*16 + sub)*8 + (e&7)
#define XCD_DECODE(SUB_NS_BITS)                                                              \
  int bid = blockIdx.x;                                                                      \
  int q_ = bid >> 3, sub_ = q_ & 15;                                                         \
  int e = ((q_ >> 4) << 3) | (bid & 7);                                                      \
  int ns = sub_ & ((1 << (SUB_NS_BITS)) - 1);                                                \
  int mz = sub_ >> (SUB_NS_BITS);

// ---------------- up-projection: scores[slot] = relu(xb[t] @ kb[e]^T) * gate ----------------
__global__ __launch_bounds__(256, 2) void k_up(
    const u16* __restrict__ xb, const u16* __restrict__ kb,
    const float* __restrict__ selval, const int* __restrict__ cnt,
    const int* __restrict__ bucket, const u16* __restrict__ zeros,
    u16* __restrict__ scores)
{
  XCD_DECODE(2);                       // 4 ns x 4 mz
  int ne = cnt[e];
  if ((mz << 7) >= ne) return;
  int nb0 = ns << 7;
  int tid = threadIdx.x, l = tid & 63, w = tid >> 6;

  __shared__ __align__(16) u16 Ab[2][8192];
  __shared__ __align__(16) u16 Bb[2][8192];
  __shared__ int slot_l[128];
  __shared__ float gate_l[128];

  GEMM_MACROS;

  const char* gB[4];
#pragma unroll
  for (int i = 0; i < 4; ++i) {
    int n = nb0 + w32 + (i << 3) + (l >> 3);
    gB[i] = (const char*)(kb + ((size_t)e * ESIZE + n) * DMODEL) + lg16;
  }

  for (int mt = mz; (mt << 7) < ne; mt += 4) {
    int row0 = mt << 7;
    int rem = ne - row0; if (rem > 128) rem = 128;
    __syncthreads();
    if (tid < 128) {
      int slot = -1; float g = 0.f;
      if (tid < rem) { slot = bucket[e * TOKENS + row0 + tid]; g = selval[slot]; }
      slot_l[tid] = slot; gate_l[tid] = g;
    }
    __syncthreads();

    const char* gA[4];
#pragma unroll
    for (int i = 0; i < 4; ++i) {
      int s = slot_l[w32 + (i << 3) + (l >> 3)];
      gA[i] = ((s >= 0) ? (const char*)(xb + (size_t)(s >> 2) * DMODEL)
                        : (const char*)zeros) + lg16;
    }

    f32x4 acc[4][4];
#pragma unroll
    for (int i = 0; i < 4; ++i)
#pragma unroll
      for (int j = 0; j < 4; ++j) acc[i][j] = (f32x4){0.f, 0.f, 0.f, 0.f};

    KLOOP(16);

#pragma unroll
    for (int mi = 0; mi < 4; ++mi) {
      int rbase = wm + (mi << 4) + ((l >> 4) << 2);
#pragma unroll
      for (int rr = 0; rr < 4; ++rr) {
        int r = rbase + rr;
        if (r < rem) {
          float g = gate_l[r];
          u16* so = scores + (size_t)slot_l[r] * ESIZE + nb0 + wn + (l & 15);
#pragma unroll
          for (int ni = 0; ni < 4; ++ni)
            so[ni << 4] = f2b(fmaxf(acc[mi][ni][rr], 0.f) * g);
        }
      }
    }
  }
}

// ---------------- down-projection: stage[slot] = scores[slot] @ vb[e]^T ----------------
__global__ __launch_bounds__(256, 2) void k_down(
    const u16* __restrict__ scores, const u16* __restrict__ vb,
    const int* __restrict__ cnt, const int* __restrict__ bucket,
    const u16* __restrict__ zeros, u16* __restrict__ stage)
{
  XCD_DECODE(3);                       // 8 ns x 2 mz
  int ne = cnt[e];
  if ((mz << 7) >= ne) return;
  int nb0 = ns << 7;
  int tid = threadIdx.x, l = tid & 63, w = tid >> 6;

  __shared__ __align__(16) u16 Ab[2][8192];
  __shared__ __align__(16) u16 Bb[2][8192];
  __shared__ int slot_l[128];

  GEMM_MACROS;

  const char* gB[4];
#pragma unroll
  for (int i = 0; i < 4; ++i) {
    int n = nb0 + w32 + (i << 3) + (l >> 3);
    gB[i] = (const char*)(vb + ((size_t)e * DMODEL + n) * ESIZE) + lg16;
  }

  for (int mt = mz; (mt << 7) < ne; mt += 2) {
    int row0 = mt << 7;
    int rem = ne - row0; if (rem > 128) rem = 128;
    __syncthreads();
    if (tid < 128) {
      int slot = -1;
      if (tid < rem) slot = bucket[e * TOKENS + row0 + tid];
      slot_l[tid] = slot;
    }
    __syncthreads();

    const char* gA[4];
#pragma unroll
    for (int i = 0; i < 4; ++i) {
      int s = slot_l[w32 + (i << 3) + (l >> 3)];
      gA[i] = ((s >= 0) ? (const char*)(scores + (size_t)s * ESIZE)
                        : (const char*)zeros) + lg16;
    }

    f32x4 acc[4][4];
#pragma unroll
    for (int i = 0; i < 4; ++i)
#pragma unroll
      for (int j = 0; j < 4; ++j) acc[i][j] = (f32x4){0.f, 0.f, 0.f, 0.f};

    KLOOP(8);

#pragma unroll
    for (int mi = 0; mi < 4; ++mi) {
      int rbase = wm + (mi << 4) + ((l >> 4) << 2);
#pragma unroll
      for (int rr = 0; rr < 4; ++rr) {
        int r = rbase + rr;
        if (r < rem) {
          u16* so = stage + (size_t)slot_l[r] * DMODEL + nb0 + wn + (l & 15);
#pragma unroll
          for (int ni = 0; ni < 4; ++ni)
            so[ni << 4] = f2b(acc[mi][ni][rr]);
        }
      }
    }
  }
}

// ---------------- final: out[t] = sum_h stage[t*4+h] ----------------
__global__ __launch_bounds__(256) void k_final(const u16* __restrict__ stage,
                                               float* __restrict__ out)
{
  int tid = threadIdx.x;
  int t = (blockIdx.x << 1) + (tid >> 7);
  int d0 = (tid & 127) << 3;
  const u16* r0 = stage + ((size_t)t << 12) + d0;
  uint4 a0 = *(const uint4*)(r0);
  uint4 a1 = *(const uint4*)(r0 + 1024);
  uint4 a2 = *(const uint4*)(r0 + 2048);
  uint4 a3 = *(const uint4*)(r0 + 3072);
  float4 lo4, hi4;
  lo4.x = blo(a0.x) + blo(a1.x) + blo(a2.x) + blo(a3.x);
  lo4.y = bhi(a0.x) + bhi(a1.x) + bhi(a2.x) + bhi(a3.x);
  lo4.z = blo(a0.y) + blo(a1.y) + blo(a2.y) + blo(a3.y);
  lo4.w = bhi(a0.y) + bhi(a1.y) + bhi(a2.y) + bhi(a3.y);
  hi4.x = blo(a0.z) + blo(a1.z) + blo(a2.z) + blo(a3.z);
  hi4.y = bhi(a0.z) + bhi(a1.z) + bhi(a2.z) + bhi(a3.z);
  hi4.z = blo(a0.w) + blo(a1.w) + blo(a2.w) + blo(a3.w);
  hi4.w = bhi(a0.w) + bhi(a1.w) + bhi(a2.w) + bhi(a3.w);
  float* o = out + (size_t)t * DMODEL + d0;
  *(float4*)o = lo4;
  *(float4*)(o + 4) = hi4;
}

// ================= fallback (reg-staged) kernels, used if ws too small =================
__global__ __launch_bounds__(256, 2) void k_up_rs(
    const float* __restrict__ x, const float* __restrict__ keys,
    const float* __restrict__ selval, const int* __restrict__ cnt,
    const int* __restrict__ bucket, u16* __restrict__ scores)
{
  int bid = blockIdx.x;
  int pair = bid & 127, mz = bid >> 7;
  int e = pair >> 2, ns = pair & 3;
  int ne = cnt[e];
  if ((mz << 7) >= ne) return;
  int nb0 = ns << 7;
  int tid = threadIdx.x;

  __shared__ __align__(16) u16 Abuf[2][128 * 72];
  __shared__ __align__(16) u16 Bbuf[2][128 * 72];
  __shared__ int slot_l[128];
  __shared__ float gate_l[128];

  const float* Kb = keys + (size_t)e * (DMODEL * ESIZE) + nb0;
  int arow = tid >> 1, ac0 = (tid & 1) << 5;
  int bn = tid & 31, bk0 = (tid >> 5) << 3;
  int lane = tid & 63, w = tid >> 6;
  int wm = (w >> 1) << 6, wn = (w & 1) << 6;

  for (int mt = mz; (mt << 7) < ne; mt += 4) {
    int row0 = mt << 7;
    int rem = ne - row0; if (rem > 128) rem = 128;
    __syncthreads();
    if (tid < 128) {
      int slot = -1; float g = 0.f;
      if (tid < rem) { slot = bucket[e * TOKENS + row0 + tid]; g = selval[slot]; }
      slot_l[tid] = slot; gate_l[tid] = g;
    }
    __syncthreads();

    int aslot = slot_l[arow];
    const float* xr = (aslot >= 0) ? (x + (size_t)(aslot >> 2) * DMODEL + ac0) : nullptr;
    const float* bp = Kb + (size_t)bk0 * ESIZE + (bn << 2);

    f32x4 acc[4][4];
#pragma unroll
    for (int i = 0; i < 4; ++i)
#pragma unroll
      for (int j = 0; j < 4; ++j) acc[i][j] = (f32x4){0.f, 0.f, 0.f, 0.f};

    float4 ar[8], br[8];
#define LOADA_UP(K) do { if (xr) { const float4* p_ = (const float4*)(xr + (K)); \
    _Pragma("unroll") for (int i_ = 0; i_ < 8; ++i_) ar[i_] = p_[i_]; } \
    else { _Pragma("unroll") for (int i_ = 0; i_ < 8; ++i_) ar[i_] = make_float4(0.f,0.f,0.f,0.f); } } while (0)
#define LOADB_RS(K, LDB) do { const float* q_ = bp + (size_t)(K) * (LDB); \
    _Pragma("unroll") for (int r_ = 0; r_ < 8; ++r_) br[r_] = *(const float4*)(q_ + (size_t)r_ * (LDB)); } while (0)
#define CVTWR_A(NB) do { _Pragma("unroll") for (int g_ = 0; g_ < 4; ++g_) { \
    u32 q0_ = pk2(ar[2*g_].x, ar[2*g_].y),   q1_ = pk2(ar[2*g_].z, ar[2*g_].w); \
    u32 q2_ = pk2(ar[2*g_+1].x, ar[2*g_+1].y), q3_ = pk2(ar[2*g_+1].z, ar[2*g_+1].w); \
    *(uint4*)&Abuf[NB][swz(arow, ac0 + 8*g_)] = make_uint4(q0_,q1_,q2_,q3_); } } while (0)
#define CVTWR_B(NB) do { \
    { u32 q0_=pk2(br[0].x,br[1].x),q1_=pk2(br[2].x,br[3].x),q2_=pk2(br[4].x,br[5].x),q3_=pk2(br[6].x,br[7].x); \
      *(uint4*)&Bbuf[NB][swz((bn<<2)+0, bk0)] = make_uint4(q0_,q1_,q2_,q3_); } \
    { u32 q0_=pk2(br[0].y,br[1].y),q1_=pk2(br[2].y,br[3].y),q2_=pk2(br[4].y,br[5].y),q3_=pk2(br[6].y,br[7].y); \
      *(uint4*)&Bbuf[NB][swz((bn<<2)+1, bk0)] = make_uint4(q0_,q1_,q2_,q3_); } \
    { u32 q0_=pk2(br[0].z,br[1].z),q1_=pk2(br[2].z,br[3].z),q2_=pk2(br[4].z,br[5].z),q3_=pk2(br[6].z,br[7].z); \
      *(uint4*)&Bbuf[NB][swz((bn<<2)+2, bk0)] = make_uint4(q0_,q1_,q2_,q3_); } \
    { u32 q0_=pk2(br[0].w,br[1].w),q1_=pk2(br[2].w,br[3].w),q2_=pk2(br[4].w,br[5].w),q3_=pk2(br[6].w,br[7].w); \
      *(uint4*)&Bbuf[NB][swz((bn<<2)+3, bk0)] = make_uint4(q0_,q1_,q2_,q3_); } } while (0)
#define MFMA_RS(CUR) do { _Pragma("unroll") for (int kh_ = 0; kh_ < 2; ++kh_) { \
    int kk_ = (kh_ << 5) | ((lane >> 4) << 3); \
    bf16x8 af_[4], bf_[4]; \
    _Pragma("unroll") for (int mi_ = 0; mi_ < 4; ++mi_) \
      af_[mi_] = *(const bf16x8*)&Abuf[CUR][swz(wm + (mi_ << 4) + (lane & 15), kk_)]; \
    _Pragma("unroll") for (int ni_ = 0; ni_ < 4; ++ni_) \
      bf_[ni_] = *(const bf16x8*)&Bbuf[CUR][swz(wn + (ni_ << 4) + (lane & 15), kk_)]; \
    _Pragma("unroll") for (int mi_ = 0; mi_ < 4; ++mi_) \
      _Pragma("unroll") for (int ni_ = 0; ni_ < 4; ++ni_) \
        acc[mi_][ni_] = __builtin_amdgcn_mfma_f32_16x16x32_bf16(af_[mi_], bf_[ni_], acc[mi_][ni_], 0, 0, 0); \
  } } while (0)

    LOADA_UP(0); LOADB_RS(0, ESIZE);
    CVTWR_A(0); CVTWR_B(0);
    __syncthreads();
    int cur = 0;
    for (int k0 = 0; k0 < DMODEL; k0 += 64) {
      bool late = (k0 + 64 >= DMODEL);
      if (!late) { LOADA_UP(k0 + 64); LOADB_RS(k0 + 64, ESIZE); }
      MFMA_RS(cur);
      if (!late) { CVTWR_A(cur ^ 1); CVTWR_B(cur ^ 1); }
      __syncthreads();
      cur ^= 1;
    }

#pragma unroll
    for (int mi = 0; mi < 4; ++mi) {
      int rbase = wm + (mi << 4) + ((lane >> 4) << 2);
#pragma unroll
      for (int rr = 0; rr < 4; ++rr) {
        int r = rbase + rr;
        if (r < rem) {
          float g = gate_l[r];
          u16* so = scores + (size_t)slot_l[r] * ESIZE + nb0 + wn + (lane & 15);
#pragma unroll
          for (int ni = 0; ni < 4; ++ni)
            so[ni << 4] = f2b(fmaxf(acc[mi][ni][rr], 0.f) * g);
        }
      }
    }
#undef LOADA_UP
#undef LOADB_RS
#undef CVTWR_A
#undef CVTWR_B
#undef MFMA_RS
  }
}

__global__ __launch_bounds__(256, 2) void k_down_rs(
    const u16* __restrict__ scores, const float* __restrict__ values,
    const int* __restrict__ cnt, const int* __restrict__ bucket,
    u16* __restrict__ stage, float* __restrict__ out)
{
  int bid = blockIdx.x;
  int pair = bid & 255, mz = bid >> 8;
  int e = pair >> 3, ns = pair & 7;
  int ne = cnt[e];
  if ((mz << 7) >= ne) return;
  int nb0 = ns << 7;
  int tid = threadIdx.x;

  __shared__ __align__(16) u16 Abuf[2][128 * 72];
  __shared__ __align__(16) u16 Bbuf[2][128 * 72];
  __shared__ int slot_l[128];

  const float* Vb = values + (size_t)e * (ESIZE * DMODEL) + nb0;
  int arow = tid >> 1, ac0 = (tid & 1) << 5;
  int bn = tid & 31, bk0 = (tid >> 5) << 3;
  int lane = tid & 63, w = tid >> 6;
  int wm = (w >> 1) << 6, wn = (w & 1) << 6;

  for (int mt = mz; (mt << 7) < ne; mt += 2) {
    int row0 = mt << 7;
    int rem = ne - row0; if (rem > 128) rem = 128;
    __syncthreads();
    if (tid < 128) {
      int slot = -1;
      if (tid < rem) slot = bucket[e * TOKENS + row0 + tid];
      slot_l[tid] = slot;
    }
    __syncthreads();

    int aslot = slot_l[arow];
    const u16* sr = (aslot >= 0) ? (scores + (size_t)aslot * ESIZE + ac0) : nullptr;
    const float* bp = Vb + (size_t)bk0 * DMODEL + (bn << 2);

    f32x4 acc[4][4];
#pragma unroll
    for (int i = 0; i < 4; ++i)
#pragma unroll
      for (int j = 0; j < 4; ++j) acc[i][j] = (f32x4){0.f, 0.f, 0.f, 0.f};

    uint4 a4[4]; float4 br[8];
#define LOADA_DN(K) do { if (sr) { const uint4* p_ = (const uint4*)(sr + (K)); \
    _Pragma("unroll") for (int i_ = 0; i_ < 4; ++i_) a4[i_] = p_[i_]; } \
    else { _Pragma("unroll") for (int i_ = 0; i_ < 4; ++i_) a4[i_] = make_uint4(0,0,0,0); } } while (0)
#define LOADB_RS(K, LDB) do { const float* q_ = bp + (size_t)(K) * (LDB); \
    _Pragma("unroll") for (int r_ = 0; r_ < 8; ++r_) br[r_] = *(const float4*)(q_ + (size_t)r_ * (LDB)); } while (0)
#define WR_A(NB) do { _Pragma("unroll") for (int g_ = 0; g_ < 4; ++g_) \
    *(uint4*)&Abuf[NB][swz(arow, ac0 + 8*g_)] = a4[g_]; } while (0)
#define CVTWR_B(NB) do { \
    { u32 q0_=pk2(br[0].x,br[1].x),q1_=pk2(br[2].x,br[3].x),q2_=pk2(br[4].x,br[5].x),q3_=pk2(br[6].x,br[7].x); \
      *(uint4*)&Bbuf[NB][swz((bn<<2)+0, bk0)] = make_uint4(q0_,q1_,q2_,q3_); } \
    { u32 q0_=pk2(br[0].y,br[1].y),q1_=pk2(br[2].y,br[3].y),q2_=pk2(br[4].y,br[5].y),q3_=pk2(br[6].y,br[7].y); \
      *(uint4*)&Bbuf[NB][swz((bn<<2)+1, bk0)] = make_uint4(q0_,q1_,q2_,q3_); } \
    { u32 q0_=pk2(br[0].z,br[1].z),q1_=pk2(br[2].z,br[3].z),q2_=pk2(br[4].z,br[5].z),q3_=pk2(br[6].z,br[7].z); \
      *(uint4*)&Bbuf[NB][swz((bn<<2)+2, bk0)] = make_uint4(q0_,q1_,q2_,q3_); } \
    { u32 q0_=pk2(br[0].w,br[1].w),q1_=pk2(br[2].w,br[3].w),q2_=pk2(br[4].w,br[5].w),q3_=pk2(br[6].w,br[7].w); \
      *(uint4*)&Bbuf[NB][swz((bn<<2)+3, bk0)] = make_uint4(q0_,q1_,q2_,q3_); } } while (0)
#define MFMA_RS(CUR) do { _Pragma("unroll") for (int kh_ = 0; kh_ < 2; ++kh_) { \
    int kk_ = (kh_ << 5) | ((lane >> 4) << 3); \
    bf16x8 af_[4], bf_[4]; \
    _Pragma("unroll") for (int mi_ = 0; mi_ < 4; ++mi_) \
      af_[mi_] = *(const bf16x8*)&Abuf[CUR][swz(wm + (mi_ << 4) + (lane & 15), kk_)]; \
    _Pragma("unroll") for (int ni_ = 0; ni_ < 4; ++ni_) \
      bf_[ni_] = *(const bf16x8*)&Bbuf[CUR][swz(wn + (ni_ << 4) + (lane & 15), kk_)]; \
    _Pragma("unroll") for (int mi_ = 0; mi_ < 4; ++mi_) \
      _Pragma("unroll") for (int ni_ = 0; ni_ < 4; ++ni_) \
        acc[mi_][ni_] = __builtin_amdgcn_mfma_f32_16x16x32_bf16(af_[mi_], bf_[ni_], acc[mi_][ni_], 0, 0, 0); \
  } } while (0)

    LOADA_DN(0); LOADB_RS(0, DMODEL);
    WR_A(0); CVTWR_B(0);
    __syncthreads();
    int cur = 0;
    for (int k0 = 0; k0 < ESIZE; k0 += 64) {
      bool late = (k0 + 64 >= ESIZE);
      if (!late) { LOADA_DN(k0 + 64); LOADB_RS(k0 + 64, DMODEL); }
      MFMA_RS(cur);
      if (!late) { WR_A(cur ^ 1); CVTWR_B(cur ^ 1); }
      __syncthreads();
      cur ^= 1;
    }

#pragma unroll
    for (int mi = 0; mi < 4; ++mi) {
      int rbase = wm + (mi << 4) + ((lane >> 4) << 2);
#pragma unroll
      for (int rr = 0; rr < 4; ++rr) {
        int r = rbase + rr;
        if (r < rem) {
          if (stage) {
            u16* so = stage + (size_t)slot_l[r] * DMODEL + nb0 + wn + (lane & 15);
#pragma unroll
            for (int ni = 0; ni < 4; ++ni)
              so[ni << 4] = f2b(acc[mi][ni][rr]);
          } else {
            int t = slot_l[r] >> 2;
            float* oo = out + (size_t)t * DMODEL + nb0 + wn + (lane & 15);
#pragma unroll
            for (int ni = 0; ni < 4; ++ni)
              atomicAdd(&oo[ni << 4], acc[mi][ni][rr]);
          }
        }
      }
    }
#undef LOADA_DN
#undef LOADB_RS
#undef WR_A
#undef CVTWR_B
#undef MFMA_RS
  }
}

extern "C" void kernel_launch(void* const* d_in, const int* in_sizes, int n_in,
                              void* d_out, int out_size, void* d_ws, size_t ws_size,
                              hipStream_t stream) {
  (void)in_sizes; (void)n_in;
  const float* x      = (const float*)d_in[0];
  const float* keys   = (const float*)d_in[1];
  const float* values = (const float*)d_in[2];
  const float* es     = (const float*)d_in[3];
  float* out = (float*)d_out;

  char* W = (char*)d_ws;
  int*   cnt       = (int*)W;                        // 128 B
  u16*   zeros     = (u16*)(W + 4 * 1024);           // 4 KB
  u32*   selpk     = (u32*)(W + 16 * 1024);          // 16 KB
  float* selval    = (float*)(W + 64 * 1024);        // 64 KB
  float* blockpart = (float*)(W + 128 * 1024);       // 64 KB f32 [512][32]
  int*   bucket    = (int*)(W + 512 * 1024);         // 512 KB
  float* esT4      = (float*)(W + 1280 * 1024);      // 128 KB f32 [256][32][4]

  bool big = ws_size >= (90ull << 20);

  k_esT<<<32, 256, 0, stream>>>(es, esT4);

  if (big) {
    u16* xb     = (u16*)(W + 2ull * 1024 * 1024);    // 8 MB  bf16 [4096][1024]
    u16* scores = (u16*)(W + 10ull * 1024 * 1024);   // 16 MB bf16 [16384][512]
    u16* kb     = (u16*)(W + 26ull * 1024 * 1024);   // 32 MB bf16 [32][512][1024]
    u16* vb     = (u16*)(W + 58ull * 1024 * 1024);   // 32 MB bf16 [32][1024][512]
    u16* stage  = kb;  // aliases kb: kb dead after k_up, stage written by k_down
    hipMemsetAsync(zeros, 0, 4096, stream);
    // route (512, first) ∥ keys-tr pairs (2048) ∥ values-tr pairs (2048)
    k_mega1<<<4608, 256, 0, stream>>>(
        x, esT4, selval, selpk, blockpart, xb, keys, values, kb, vb);
    k_cf<<<1, 1024, 0, stream>>>(selpk, cnt, bucket, blockpart,
                                 out + (size_t)out_size - 1);
    k_up<<<512, 256, 0, stream>>>(xb, kb, selval, cnt, bucket, zeros, scores);
    k_down<<<512, 256, 0, stream>>>(scores, vb, cnt, bucket, zeros, stage);
    k_final<<<TOKENS / 2, 256, 0, stream>>>(stage, out);
  } else {
    u16* scores = (u16*)(W + 2ull * 1024 * 1024);
    bool big50 = ws_size >= (50ull << 20);
    u16* stage = big50 ? (u16*)(W + 18ull * 1024 * 1024) : nullptr;
    if (!big50)
      hipMemsetAsync(d_out, 0, (size_t)out_size * sizeof(float), stream);
    k_mega1<<<512, 256, 0, stream>>>(
        x, esT4, selval, selpk, blockpart, nullptr, nullptr, nullptr, nullptr, nullptr);
    k_cf<<<1, 1024, 0, stream>>>(selpk, cnt, bucket, blockpart,
                                 out + (size_t)out_size - 1);
    k_up_rs<<<512, 256, 0, stream>>>(x, keys, selval, cnt, bucket, scores);
    k_down_rs<<<512, 256, 0, stream>>>(scores, values, cnt, bucket, stage, out);
    if (big50)
      k_final<<<TOKENS / 2, 256, 0, stream>>>(stage, out);
  }
}

// Round 15
// 165.664 us; speedup vs baseline: 1.1645x; 1.0718x over previous
//
#include <hip/hip_runtime.h>
#include <hip/hip_bf16.h>

typedef unsigned short u16;
typedef unsigned int u32;
typedef __attribute__((ext_vector_type(4))) float f32x4;
typedef __attribute__((ext_vector_type(8))) short bf16x8;

#define TOKENS 4096
#define DMODEL 1024
#define NEXP 32
#define ESIZE 512

// round-to-nearest-even f32 -> bf16 bits
__device__ __forceinline__ u16 f2b(float f) {
  union { float f; u32 u; } v; v.f = f;
  u32 u = v.u;
  return (u16)((u + 0x7fffu + ((u >> 16) & 1u)) >> 16);
}

// packed f32x2 -> bf16x2
__device__ __forceinline__ u32 pk2(float a, float b) {
  union { __hip_bfloat162 h; u32 u; } v;
  v.h = __float22bfloat162_rn(make_float2(a, b));
  return v.u;
}

__device__ __forceinline__ float blo(u32 w) { union { u32 u; float f; } v; v.u = w << 16; return v.f; }
__device__ __forceinline__ float bhi(u32 w) { union { u32 u; float f; } v; v.u = w & 0xffff0000u; return v.f; }

// async global->LDS, 16B per lane; LDS dest = wave-uniform base + lane*16
typedef __attribute__((address_space(1))) const void as1_void;
typedef __attribute__((address_space(3))) void as3_void;
__device__ __forceinline__ void gl16(const void* g, void* l) {
  __builtin_amdgcn_global_load_lds((as1_void*)g, (as3_void*)l, 16, 0, 0);
}

// stride-72 swizzled LDS addr (shorts) for fallback reg-staged tiles
__device__ __forceinline__ int swz(int row, int kk) {
  return row * 72 + ((((kk >> 3) ^ (row >> 2)) & 7) << 3) + (kk & 7);
}

// ---------------- es transpose: esT4[dblk][e][j] = es[e][4*dblk+j] ----------------
__global__ __launch_bounds__(256) void k_esT(const float* __restrict__ es,
                                             float* __restrict__ esT4)
{
  int tid = threadIdx.x;
  int dblk = (blockIdx.x << 3) + (tid >> 5);
  int e = tid & 31;
  float4 v = *(const float4*)(es + (size_t)e * DMODEL + (dblk << 2));
  *((float4*)esT4 + (size_t)dblk * 32 + e) = v;
}

// ---------------- transpose-convert (round-11 proven): one 64x64 tile per block ----
__device__ __forceinline__ void tr_tile(const float* __restrict__ src,
                                        u16* __restrict__ dst, int R, int C,
                                        int cx, int cy, int e, int t, float* smemf)
{
  float (*tile)[68] = (float(*)[68])smemf;   // 64*68*4 = 17408 B
  int r0 = cy << 6, c0 = cx << 6;
  int rr = t >> 2, cb = (t & 3) << 4;
  const float* sp = src + ((size_t)e * R + r0 + rr) * C + c0 + cb;
#pragma unroll
  for (int j = 0; j < 4; ++j)
    *(float4*)&tile[rr][cb + (j << 2)] = *(const float4*)(sp + (j << 2));
  __syncthreads();
  int wr = t >> 2, wb = (t & 3) << 4;
  u32 q[8];
#pragma unroll
  for (int j = 0; j < 8; ++j)
    q[j] = pk2(tile[wb + (j << 1)][wr], tile[wb + (j << 1) + 1][wr]);
  u16* dp = dst + ((size_t)e * C + c0 + wr) * R + r0 + wb;
  *(uint4*)dp = make_uint4(q[0], q[1], q[2], q[3]);
  *(uint4*)(dp + 8) = make_uint4(q[4], q[5], q[6], q[7]);
}

// ---------------- mega1: route (0..511) ∥ keys-tr (512..4607) ∥ values-tr ------
__global__ __launch_bounds__(256) void k_mega1(
    const float* __restrict__ x, const float* __restrict__ esT4,
    float* __restrict__ selval, u32* __restrict__ selpk,
    float* __restrict__ blockpart, u16* __restrict__ xb,
    const float* __restrict__ keys, const float* __restrict__ values,
    u16* __restrict__ kb, u16* __restrict__ vb)
{
  __shared__ __align__(16) float smem[4352];   // 17408 B union
  int bid = blockIdx.x;
  int tid = threadIdx.x;

  if (bid >= 512 + 4096) {          // values-tr
    int i = bid - (512 + 4096);
    tr_tile(values, vb, ESIZE, DMODEL, i & 15, (i >> 4) & 7, i >> 7, tid, smem);
    return;
  }
  if (bid >= 512) {                 // keys-tr
    int i = bid - 512;
    tr_tile(keys, kb, DMODEL, ESIZE, i & 7, (i >> 3) & 15, i >> 7, tid, smem);
    return;
  }

  // ---- routing: K-split across 4 waves, 8 tokens/block ----
  float (*part)[8][32] = (float(*)[8][32])smem;          // 4 KB
  float (*ps)[32] = (float(*)[32])(smem + 1024);         // 1 KB
  int w = tid >> 6, lane = tid & 63;
  int e = lane & 31, h = lane >> 5;
  int t0 = bid << 3;

  const float4* ev = (const float4*)esT4 + (size_t)((w << 6) + (h << 5)) * 32 + e;
  const float4* xv = (const float4*)x + ((size_t)t0 << 8) + (w << 6) + (h << 5);

  float acc[8];
#pragma unroll
  for (int tk = 0; tk < 8; ++tk) acc[tk] = 0.f;

#pragma unroll 2
  for (int i = 0; i < 32; ++i) {
    float4 b = ev[(size_t)i * 32];
#pragma unroll
    for (int tk = 0; tk < 8; ++tk) {
      float4 a = xv[(tk << 8) + i];
      acc[tk] += a.x * b.x + a.y * b.y + a.z * b.z + a.w * b.w;
    }
  }
#pragma unroll
  for (int tk = 0; tk < 8; ++tk) {
    float s = acc[tk] + __shfl_xor(acc[tk], 32);
    if (h == 0) part[w][tk][e] = s;
  }
  __syncthreads();

  int tk = tid >> 5, ge = tid & 31;
  {
    float r = part[0][tk][ge] + part[1][tk][ge] + part[2][tk][ge] + part[3][tk][ge];
    int t = t0 + tk;

    float m = r;
#pragma unroll
    for (int mk = 16; mk; mk >>= 1) m = fmaxf(m, __shfl_xor(m, mk));
    float sx = __expf(r - m);
#pragma unroll
    for (int mk = 16; mk; mk >>= 1) sx += __shfl_xor(sx, mk);
    ps[tk][ge] = __expf(r - (m + __logf(sx)));

    u32 packed = 0;
    float v = r;
#pragma unroll
    for (int it = 0; it < 4; ++it) {
      float bv = v; int bi = ge;
#pragma unroll
      for (int mk = 16; mk; mk >>= 1) {
        float ov = __shfl_xor(bv, mk); int oi = __shfl_xor(bi, mk);
        if (ov > bv || (ov == bv && oi < bi)) { bv = ov; bi = oi; }
      }
      packed |= (u32)bi << (8 * it);
      if (ge == it) selval[t * 4 + it] = 1.f / (1.f + __expf(-bv));
      if (ge == bi) v = -3.0e38f;
    }
    if (ge == 0) selpk[t] = packed;
  }
  __syncthreads();
  if (tid < 32) {
    float s = 0.f;
#pragma unroll
    for (int j = 0; j < 8; ++j) s += ps[j][tid];
    blockpart[bid * 32 + tid] = s;
  }

  // fused x -> bf16 for this block's 8 rows (coalesced)
  if (xb) {
    const float4* src = (const float4*)x + ((size_t)bid << 11);
    u16* dst = xb + ((size_t)bid << 13);
#pragma unroll
    for (int j = 0; j < 8; ++j) {
      int idx = (j << 8) + tid;
      float4 a = src[idx];
      *(uint2*)(dst + (idx << 2)) = make_uint2(pk2(a.x, a.y), pk2(a.z, a.w));
    }
  }
}

// ---------------- bucket build + entropy regularizer (merged, uniform barriers) ----
__global__ __launch_bounds__(1024) void k_cf(
    const u32* __restrict__ selpk, int* __restrict__ cnt, int* __restrict__ bucket,
    const float* __restrict__ blockpart, float* __restrict__ out_reg)
{
  __shared__ int cl[32];
  __shared__ float pf[32][33];
  int tid = threadIdx.x;
  if (tid < 32) cl[tid] = 0;
  __syncthreads();
  int ex[16], pos[16];
#pragma unroll
  for (int j = 0; j < 4; ++j) {
    int t = tid + (j << 10);
    u32 pk = selpk[t];
#pragma unroll
    for (int h = 0; h < 4; ++h) {
      int e = (pk >> (8 * h)) & 0xff;
      ex[j * 4 + h] = e;
      pos[j * 4 + h] = atomicAdd(&cl[e], 1);
    }
  }
#pragma unroll
  for (int j = 0; j < 4; ++j) {
    int t = tid + (j << 10);
#pragma unroll
    for (int h = 0; h < 4; ++h)
      bucket[ex[j * 4 + h] * TOKENS + pos[j * 4 + h]] = (t << 2) | h;
  }
  __syncthreads();
  if (tid < 32) cnt[tid] = cl[tid];

  // fin: colsum over 512 blockparts
  int e = tid & 31, c = tid >> 5;
  float s = 0.f;
  for (int b = c; b < 512; b += 32) s += blockpart[b * 32 + e];
  pf[c][e] = s;
  __syncthreads();
  if (tid < 32) {
    float S = 0.f;
#pragma unroll
    for (int i = 0; i < 32; ++i) S += pf[i][tid];
    float Pm = S * (1.0f / TOKENS);
    float rp = __logf(Pm) * Pm;
#pragma unroll
    for (int mk = 16; mk; mk >>= 1) rp += __shfl_xor(rp, mk);
    if (tid == 0) *out_reg = rp;
  }
}

// ======== fast GEMMs: BK=32, 4 blocks/CU (~33KB LDS), global_load_lds staging,
// XOR-granule (mod-4) swizzle, 2-deep counted-vmcnt pipeline ========
// Per k-step each wave stages 32 rows x 64B per operand with TWO gl16 (16 rows each).
// Wave w covers rows 32w..32w+31; gl16 chunk i covers rows 32w+16i..+15.
// Lane l -> row-in-chunk (l>>2), LDS granule l&3 holding global granule (l&3)^((l>>2)&3).
// Read: global granule gg of row r lives at LDS granule gg^(r&3)  (involution).
#define GEMM_MACROS                                                                          \
  int wm = (w >> 1) << 6, wn = (w & 1) << 6;                                                 \
  int lsub = l >> 2;                                                                         \
  int lg16 = (((l & 3) ^ (lsub & 3)) << 4);

#define STAGE(BUF, K0) do {                                                                  \
  gl16(gA0 + ((K0) << 1), (void*)&Ab[BUF][(w << 10)]);                                       \
  gl16(gA1 + ((K0) << 1), (void*)&Ab[BUF][(w << 10) + 512]);                                 \
  gl16(gB0 + ((K0) << 1), (void*)&Bb[BUF][(w << 10)]);                                       \
  gl16(gB1 + ((K0) << 1), (void*)&Bb[BUF][(w << 10) + 512]);                                 \
} while (0)

#define COMPUTE(CUR) do {                                                                    \
  bf16x8 af_[4], bf_[4];                                                                     \
  int gg_ = l >> 4;                                                                          \
  _Pragma("unroll") for (int mi_ = 0; mi_ < 4; ++mi_) {                                      \
    int row_ = wm + (mi_ << 4) + (l & 15);                                                   \
    af_[mi_] = *(const bf16x8*)&Ab[CUR][(row_ << 5) + ((gg_ ^ (row_ & 3)) << 3)];            \
  }                                                                                          \
  _Pragma("unroll") for (int ni_ = 0; ni_ < 4; ++ni_) {                                      \
    int row_ = wn + (ni_ << 4) + (l & 15);                                                   \
    bf_[ni_] = *(const bf16x8*)&Bb[CUR][(row_ << 5) + ((gg_ ^ (row_ & 3)) << 3)];            \
  }                                                                                          \
  _Pragma("unroll") for (int mi_ = 0; mi_ < 4; ++mi_)                                        \
    _Pragma("unroll") for (int ni_ = 0; ni_ < 4; ++ni_)                                      \
      acc[mi_][ni_] = __builtin_amdgcn_mfma_f32_16x16x32_bf16(af_[mi_], bf_[ni_],            \
                                                              acc[mi_][ni_], 0, 0, 0);       \
} while (0)

// counted-vmcnt K-loop over NT tiles of 32 (4 gl16 per wave per tile)
#define KLOOP(NT) do {                                                                       \
  STAGE(0, 0);                                                                               \
  STAGE(1, 32);                                                                              \
  _Pragma("unroll 1")                                                                        \
  for (int t_ = 0; t_ < (NT); ++t_) {                                                        \
    int cur_ = t_ & 1;                                                                       \
    if (t_ + 1 < (NT)) { asm volatile("s_waitcnt vmcnt(4)" ::: "memory"); }                  \
    else               { asm volatile("s_waitcnt vmcnt(0)" ::: "memory"); }                  \
    asm volatile("s_barrier" ::: "memory");                                                  \
    COMPUTE(cur_);                                                                           \
    asm volatile("s_barrier" ::: "memory");                                                  \
    if (t_ + 2 < (NT)) STAGE(cur_, (t_ + 2) << 5);                                           \
  }                                                                                          \
} while (0)

// XCD-affine decode: bid = ((e>>3)*16 + sub)*8 + (e&7)
#define XCD_DECODE(SUB_NS_BITS)                                                              \
  int bid = blockIdx.x;                                                                      \
  int q_ = bid >> 3, sub_ = q_ & 15;                                                         \
  int e = ((q_ >> 4) << 3) | (bid & 7);                                                      \
  int ns = sub_ & ((1 << (SUB_NS_BITS)) - 1);                                                \
  int mz = sub_ >> (SUB_NS_BITS);

// ---------------- up-projection: scores[slot] = relu(xb[t] @ kb[e]^T) * gate ----------------
__global__ __launch_bounds__(256, 4) void k_up(
    const u16* __restrict__ xb, const u16* __restrict__ kb,
    const float* __restrict__ selval, const int* __restrict__ cnt,
    const int* __restrict__ bucket, const u16* __restrict__ zeros,
    u16* __restrict__ scores)
{
  XCD_DECODE(2);                       // 4 ns x 4 mz
  int ne = cnt[e];
  if ((mz << 7) >= ne) return;
  int nb0 = ns << 7;
  int tid = threadIdx.x, l = tid & 63, w = tid >> 6;

  __shared__ __align__(16) u16 Ab[2][4096];
  __shared__ __align__(16) u16 Bb[2][4096];
  __shared__ int slot_l[128];
  __shared__ float gate_l[128];

  GEMM_MACROS;

  int ra0 = (w << 5) + lsub, ra1 = ra0 + 16;
  const char* gB0 = (const char*)(kb + ((size_t)e * ESIZE + nb0 + ra0) * DMODEL) + lg16;
  const char* gB1 = gB0 + (size_t)16 * DMODEL * sizeof(u16);

  for (int mt = mz; (mt << 7) < ne; mt += 4) {
    int row0 = mt << 7;
    int rem = ne - row0; if (rem > 128) rem = 128;
    __syncthreads();
    if (tid < 128) {
      int slot = -1; float g = 0.f;
      if (tid < rem) { slot = bucket[e * TOKENS + row0 + tid]; g = selval[slot]; }
      slot_l[tid] = slot; gate_l[tid] = g;
    }
    __syncthreads();

    int s0 = slot_l[ra0], s1 = slot_l[ra1];
    const char* gA0 = ((s0 >= 0) ? (const char*)(xb + (size_t)(s0 >> 2) * DMODEL)
                                 : (const char*)zeros) + lg16;
    const char* gA1 = ((s1 >= 0) ? (const char*)(xb + (size_t)(s1 >> 2) * DMODEL)
                                 : (const char*)zeros) + lg16;

    f32x4 acc[4][4];
#pragma unroll
    for (int i = 0; i < 4; ++i)
#pragma unroll
      for (int j = 0; j < 4; ++j) acc[i][j] = (f32x4){0.f, 0.f, 0.f, 0.f};

    KLOOP(32);

#pragma unroll
    for (int mi = 0; mi < 4; ++mi) {
      int rbase = wm + (mi << 4) + ((l >> 4) << 2);
#pragma unroll
      for (int rr = 0; rr < 4; ++rr) {
        int r = rbase + rr;
        if (r < rem) {
          float g = gate_l[r];
          u16* so = scores + (size_t)slot_l[r] * ESIZE + nb0 + wn + (l & 15);
#pragma unroll
          for (int ni = 0; ni < 4; ++ni)
            so[ni << 4] = f2b(fmaxf(acc[mi][ni][rr], 0.f) * g);
        }
      }
    }
  }
}

// ---------------- down-projection: stage[slot] = scores[slot] @ vb[e]^T ----------------
__global__ __launch_bounds__(256, 4) void k_down(
    const u16* __restrict__ scores, const u16* __restrict__ vb,
    const int* __restrict__ cnt, const int* __restrict__ bucket,
    const u16* __restrict__ zeros, u16* __restrict__ stage)
{
  XCD_DECODE(3);                       // 8 ns x 2 mz
  int ne = cnt[e];
  if ((mz << 7) >= ne) return;
  int nb0 = ns << 7;
  int tid = threadIdx.x, l = tid & 63, w = tid >> 6;

  __shared__ __align__(16) u16 Ab[2][4096];
  __shared__ __align__(16) u16 Bb[2][4096];
  __shared__ int slot_l[128];

  GEMM_MACROS;

  int ra0 = (w << 5) + lsub, ra1 = ra0 + 16;
  const char* gB0 = (const char*)(vb + ((size_t)e * DMODEL + nb0 + ra0) * ESIZE) + lg16;
  const char* gB1 = gB0 + (size_t)16 * ESIZE * sizeof(u16);

  for (int mt = mz; (mt << 7) < ne; mt += 2) {
    int row0 = mt << 7;
    int rem = ne - row0; if (rem > 128) rem = 128;
    __syncthreads();
    if (tid < 128) {
      int slot = -1;
      if (tid < rem) slot = bucket[e * TOKENS + row0 + tid];
      slot_l[tid] = slot;
    }
    __syncthreads();

    int s0 = slot_l[ra0], s1 = slot_l[ra1];
    const char* gA0 = ((s0 >= 0) ? (const char*)(scores + (size_t)s0 * ESIZE)
                                 : (const char*)zeros) + lg16;
    const char* gA1 = ((s1 >= 0) ? (const char*)(scores + (size_t)s1 * ESIZE)
                                 : (const char*)zeros) + lg16;

    f32x4 acc[4][4];
#pragma unroll
    for (int i = 0; i < 4; ++i)
#pragma unroll
      for (int j = 0; j < 4; ++j) acc[i][j] = (f32x4){0.f, 0.f, 0.f, 0.f};

    KLOOP(16);

#pragma unroll
    for (int mi = 0; mi < 4; ++mi) {
      int rbase = wm + (mi << 4) + ((l >> 4) << 2);
#pragma unroll
      for (int rr = 0; rr < 4; ++rr) {
        int r = rbase + rr;
        if (r < rem) {
          u16* so = stage + (size_t)slot_l[r] * DMODEL + nb0 + wn + (l & 15);
#pragma unroll
          for (int ni = 0; ni < 4; ++ni)
            so[ni << 4] = f2b(acc[mi][ni][rr]);
        }
      }
    }
  }
}

// ---------------- final: out[t] = sum_h stage[t*4+h] ----------------
__global__ __launch_bounds__(256) void k_final(const u16* __restrict__ stage,
                                               float* __restrict__ out)
{
  int tid = threadIdx.x;
  int t = (blockIdx.x << 1) + (tid >> 7);
  int d0 = (tid & 127) << 3;
  const u16* r0 = stage + ((size_t)t << 12) + d0;
  uint4 a0 = *(const uint4*)(r0);
  uint4 a1 = *(const uint4*)(r0 + 1024);
  uint4 a2 = *(const uint4*)(r0 + 2048);
  uint4 a3 = *(const uint4*)(r0 + 3072);
  float4 lo4, hi4;
  lo4.x = blo(a0.x) + blo(a1.x) + blo(a2.x) + blo(a3.x);
  lo4.y = bhi(a0.x) + bhi(a1.x) + bhi(a2.x) + bhi(a3.x);
  lo4.z = blo(a0.y) + blo(a1.y) + blo(a2.y) + blo(a3.y);
  lo4.w = bhi(a0.y) + bhi(a1.y) + bhi(a2.y) + bhi(a3.y);
  hi4.x = blo(a0.z) + blo(a1.z) + blo(a2.z) + blo(a3.z);
  hi4.y = bhi(a0.z) + bhi(a1.z) + bhi(a2.z) + bhi(a3.z);
  hi4.z = blo(a0.w) + blo(a1.w) + blo(a2.w) + blo(a3.w);
  hi4.w = bhi(a0.w) + bhi(a1.w) + bhi(a2.w) + bhi(a3.w);
  float* o = out + (size_t)t * DMODEL + d0;
  *(float4*)o = lo4;
  *(float4*)(o + 4) = hi4;
}

// ================= fallback (reg-staged) kernels, used if ws too small =================
__global__ __launch_bounds__(256, 2) void k_up_rs(
    const float* __restrict__ x, const float* __restrict__ keys,
    const float* __restrict__ selval, const int* __restrict__ cnt,
    const int* __restrict__ bucket, u16* __restrict__ scores)
{
  int bid = blockIdx.x;
  int pair = bid & 127, mz = bid >> 7;
  int e = pair >> 2, ns = pair & 3;
  int ne = cnt[e];
  if ((mz << 7) >= ne) return;
  int nb0 = ns << 7;
  int tid = threadIdx.x;

  __shared__ __align__(16) u16 Abuf[2][128 * 72];
  __shared__ __align__(16) u16 Bbuf[2][128 * 72];
  __shared__ int slot_l[128];
  __shared__ float gate_l[128];

  const float* Kb = keys + (size_t)e * (DMODEL * ESIZE) + nb0;
  int arow = tid >> 1, ac0 = (tid & 1) << 5;
  int bn = tid & 31, bk0 = (tid >> 5) << 3;
  int lane = tid & 63, w = tid >> 6;
  int wm = (w >> 1) << 6, wn = (w & 1) << 6;

  for (int mt = mz; (mt << 7) < ne; mt += 4) {
    int row0 = mt << 7;
    int rem = ne - row0; if (rem > 128) rem = 128;
    __syncthreads();
    if (tid < 128) {
      int slot = -1; float g = 0.f;
      if (tid < rem) { slot = bucket[e * TOKENS + row0 + tid]; g = selval[slot]; }
      slot_l[tid] = slot; gate_l[tid] = g;
    }
    __syncthreads();

    int aslot = slot_l[arow];
    const float* xr = (aslot >= 0) ? (x + (size_t)(aslot >> 2) * DMODEL + ac0) : nullptr;
    const float* bp = Kb + (size_t)bk0 * ESIZE + (bn << 2);

    f32x4 acc[4][4];
#pragma unroll
    for (int i = 0; i < 4; ++i)
#pragma unroll
      for (int j = 0; j < 4; ++j) acc[i][j] = (f32x4){0.f, 0.f, 0.f, 0.f};

    float4 ar[8], br[8];
#define LOADA_UP(K) do { if (xr) { const float4* p_ = (const float4*)(xr + (K)); \
    _Pragma("unroll") for (int i_ = 0; i_ < 8; ++i_) ar[i_] = p_[i_]; } \
    else { _Pragma("unroll") for (int i_ = 0; i_ < 8; ++i_) ar[i_] = make_float4(0.f,0.f,0.f,0.f); } } while (0)
#define LOADB_RS(K, LDB) do { const float* q_ = bp + (size_t)(K) * (LDB); \
    _Pragma("unroll") for (int r_ = 0; r_ < 8; ++r_) br[r_] = *(const float4*)(q_ + (size_t)r_ * (LDB)); } while (0)
#define CVTWR_A(NB) do { _Pragma("unroll") for (int g_ = 0; g_ < 4; ++g_) { \
    u32 q0_ = pk2(ar[2*g_].x, ar[2*g_].y),   q1_ = pk2(ar[2*g_].z, ar[2*g_].w); \
    u32 q2_ = pk2(ar[2*g_+1].x, ar[2*g_+1].y), q3_ = pk2(ar[2*g_+1].z, ar[2*g_+1].w); \
    *(uint4*)&Abuf[NB][swz(arow, ac0 + 8*g_)] = make_uint4(q0_,q1_,q2_,q3_); } } while (0)
#define CVTWR_B(NB) do { \
    { u32 q0_=pk2(br[0].x,br[1].x),q1_=pk2(br[2].x,br[3].x),q2_=pk2(br[4].x,br[5].x),q3_=pk2(br[6].x,br[7].x); \
      *(uint4*)&Bbuf[NB][swz((bn<<2)+0, bk0)] = make_uint4(q0_,q1_,q2_,q3_); } \
    { u32 q0_=pk2(br[0].y,br[1].y),q1_=pk2(br[2].y,br[3].y),q2_=pk2(br[4].y,br[5].y),q3_=pk2(br[6].y,br[7].y); \
      *(uint4*)&Bbuf[NB][swz((bn<<2)+1, bk0)] = make_uint4(q0_,q1_,q2_,q3_); } \
    { u32 q0_=pk2(br[0].z,br[1].z),q1_=pk2(br[2].z,br[3].z),q2_=pk2(br[4].z,br[5].z),q3_=pk2(br[6].z,br[7].z); \
      *(uint4*)&Bbuf[NB][swz((bn<<2)+2, bk0)] = make_uint4(q0_,q1_,q2_,q3_); } \
    { u32 q0_=pk2(br[0].w,br[1].w),q1_=pk2(br[2].w,br[3].w),q2_=pk2(br[4].w,br[5].w),q3_=pk2(br[6].w,br[7].w); \
      *(uint4*)&Bbuf[NB][swz((bn<<2)+3, bk0)] = make_uint4(q0_,q1_,q2_,q3_); } } while (0)
#define MFMA_RS(CUR) do { _Pragma("unroll") for (int kh_ = 0; kh_ < 2; ++kh_) { \
    int kk_ = (kh_ << 5) | ((lane >> 4) << 3); \
    bf16x8 af_[4], bf_[4]; \
    _Pragma("unroll") for (int mi_ = 0; mi_ < 4; ++mi_) \
      af_[mi_] = *(const bf16x8*)&Abuf[CUR][swz(wm + (mi_ << 4) + (lane & 15), kk_)]; \
    _Pragma("unroll") for (int ni_ = 0; ni_ < 4; ++ni_) \
      bf_[ni_] = *(const bf16x8*)&Bbuf[CUR][swz(wn + (ni_ << 4) + (lane & 15), kk_)]; \
    _Pragma("unroll") for (int mi_ = 0; mi_ < 4; ++mi_) \
      _Pragma("unroll") for (int ni_ = 0; ni_ < 4; ++ni_) \
        acc[mi_][ni_] = __builtin_amdgcn_mfma_f32_16x16x32_bf16(af_[mi_], bf_[ni_], acc[mi_][ni_], 0, 0, 0); \
  } } while (0)

    LOADA_UP(0); LOADB_RS(0, ESIZE);
    CVTWR_A(0); CVTWR_B(0);
    __syncthreads();
    int cur = 0;
    for (int k0 = 0; k0 < DMODEL; k0 += 64) {
      bool late = (k0 + 64 >= DMODEL);
      if (!late) { LOADA_UP(k0 + 64); LOADB_RS(k0 + 64, ESIZE); }
      MFMA_RS(cur);
      if (!late) { CVTWR_A(cur ^ 1); CVTWR_B(cur ^ 1); }
      __syncthreads();
      cur ^= 1;
    }

#pragma unroll
    for (int mi = 0; mi < 4; ++mi) {
      int rbase = wm + (mi << 4) + ((lane >> 4) << 2);
#pragma unroll
      for (int rr = 0; rr < 4; ++rr) {
        int r = rbase + rr;
        if (r < rem) {
          float g = gate_l[r];
          u16* so = scores + (size_t)slot_l[r] * ESIZE + nb0 + wn + (lane & 15);
#pragma unroll
          for (int ni = 0; ni < 4; ++ni)
            so[ni << 4] = f2b(fmaxf(acc[mi][ni][rr], 0.f) * g);
        }
      }
    }
#undef LOADA_UP
#undef LOADB_RS
#undef CVTWR_A
#undef CVTWR_B
#undef MFMA_RS
  }
}

__global__ __launch_bounds__(256, 2) void k_down_rs(
    const u16* __restrict__ scores, const float* __restrict__ values,
    const int* __restrict__ cnt, const int* __restrict__ bucket,
    u16* __restrict__ stage, float* __restrict__ out)
{
  int bid = blockIdx.x;
  int pair = bid & 255, mz = bid >> 8;
  int e = pair >> 3, ns = pair & 7;
  int ne = cnt[e];
  if ((mz << 7) >= ne) return;
  int nb0 = ns << 7;
  int tid = threadIdx.x;

  __shared__ __align__(16) u16 Abuf[2][128 * 72];
  __shared__ __align__(16) u16 Bbuf[2][128 * 72];
  __shared__ int slot_l[128];

  const float* Vb = values + (size_t)e * (ESIZE * DMODEL) + nb0;
  int arow = tid >> 1, ac0 = (tid & 1) << 5;
  int bn = tid & 31, bk0 = (tid >> 5) << 3;
  int lane = tid & 63, w = tid >> 6;
  int wm = (w >> 1) << 6, wn = (w & 1) << 6;

  for (int mt = mz; (mt << 7) < ne; mt += 2) {
    int row0 = mt << 7;
    int rem = ne - row0; if (rem > 128) rem = 128;
    __syncthreads();
    if (tid < 128) {
      int slot = -1;
      if (tid < rem) slot = bucket[e * TOKENS + row0 + tid];
      slot_l[tid] = slot;
    }
    __syncthreads();

    int aslot = slot_l[arow];
    const u16* sr = (aslot >= 0) ? (scores + (size_t)aslot * ESIZE + ac0) : nullptr;
    const float* bp = Vb + (size_t)bk0 * DMODEL + (bn << 2);

    f32x4 acc[4][4];
#pragma unroll
    for (int i = 0; i < 4; ++i)
#pragma unroll
      for (int j = 0; j < 4; ++j) acc[i][j] = (f32x4){0.f, 0.f, 0.f, 0.f};

    uint4 a4[4]; float4 br[8];
#define LOADA_DN(K) do { if (sr) { const uint4* p_ = (const uint4*)(sr + (K)); \
    _Pragma("unroll") for (int i_ = 0; i_ < 4; ++i_) a4[i_] = p_[i_]; } \
    else { _Pragma("unroll") for (int i_ = 0; i_ < 4; ++i_) a4[i_] = make_uint4(0,0,0,0); } } while (0)
#define LOADB_RS(K, LDB) do { const float* q_ = bp + (size_t)(K) * (LDB); \
    _Pragma("unroll") for (int r_ = 0; r_ < 8; ++r_) br[r_] = *(const float4*)(q_ + (size_t)r_ * (LDB)); } while (0)
#define WR_A(NB) do { _Pragma("unroll") for (int g_ = 0; g_ < 4; ++g_) \
    *(uint4*)&Abuf[NB][swz(arow, ac0 + 8*g_)] = a4[g_]; } while (0)
#define CVTWR_B(NB) do { \
    { u32 q0_=pk2(br[0].x,br[1].x),q1_=pk2(br[2].x,br[3].x),q2_=pk2(br[4].x,br[5].x),q3_=pk2(br[6].x,br[7].x); \
      *(uint4*)&Bbuf[NB][swz((bn<<2)+0, bk0)] = make_uint4(q0_,q1_,q2_,q3_); } \
    { u32 q0_=pk2(br[0].y,br[1].y),q1_=pk2(br[2].y,br[3].y),q2_=pk2(br[4].y,br[5].y),q3_=pk2(br[6].y,br[7].y); \
      *(uint4*)&Bbuf[NB][swz((bn<<2)+1, bk0)] = make_uint4(q0_,q1_,q2_,q3_); } \
    { u32 q0_=pk2(br[0].z,br[1].z),q1_=pk2(br[2].z,br[3].z),q2_=pk2(br[4].z,br[5].z),q3_=pk2(br[6].z,br[7].z); \
      *(uint4*)&Bbuf[NB][swz((bn<<2)+2, bk0)] = make_uint4(q0_,q1_,q2_,q3_); } \
    { u32 q0_=pk2(br[0].w,br[1].w),q1_=pk2(br[2].w,br[3].w),q2_=pk2(br[4].w,br[5].w),q3_=pk2(br[6].w,br[7].w); \
      *(uint4*)&Bbuf[NB][swz((bn<<2)+3, bk0)] = make_uint4(q0_,q1_,q2_,q3_); } } while (0)
#define MFMA_RS(CUR) do { _Pragma("unroll") for (int kh_ = 0; kh_ < 2; ++kh_) { \
    int kk_ = (kh_ << 5) | ((lane >> 4) << 3); \
    bf16x8 af_[4], bf_[4]; \
    _Pragma("unroll") for (int mi_ = 0; mi_ < 4; ++mi_) \
      af_[mi_] = *(const bf16x8*)&Abuf[CUR][swz(wm + (mi_ << 4) + (lane & 15), kk_)]; \
    _Pragma("unroll") for (int ni_ = 0; ni_ < 4; ++ni_) \
      bf_[ni_] = *(const bf16x8*)&Bbuf[CUR][swz(wn + (ni_ << 4) + (lane & 15), kk_)]; \
    _Pragma("unroll") for (int mi_ = 0; mi_ < 4; ++mi_) \
      _Pragma("unroll") for (int ni_ = 0; ni_ < 4; ++ni_) \
        acc[mi_][ni_] = __builtin_amdgcn_mfma_f32_16x16x32_bf16(af_[mi_], bf_[ni_], acc[mi_][ni_], 0, 0, 0); \
  } } while (0)

    LOADA_DN(0); LOADB_RS(0, DMODEL);
    WR_A(0); CVTWR_B(0);
    __syncthreads();
    int cur = 0;
    for (int k0 = 0; k0 < ESIZE; k0 += 64) {
      bool late = (k0 + 64 >= ESIZE);
      if (!late) { LOADA_DN(k0 + 64); LOADB_RS(k0 + 64, DMODEL); }
      MFMA_RS(cur);
      if (!late) { WR_A(cur ^ 1); CVTWR_B(cur ^ 1); }
      __syncthreads();
      cur ^= 1;
    }

#pragma unroll
    for (int mi = 0; mi < 4; ++mi) {
      int rbase = wm + (mi << 4) + ((lane >> 4) << 2);
#pragma unroll
      for (int rr = 0; rr < 4; ++rr) {
        int r = rbase + rr;
        if (r < rem) {
          if (stage) {
            u16* so = stage + (size_t)slot_l[r] * DMODEL + nb0 + wn + (lane & 15);
#pragma unroll
            for (int ni = 0; ni < 4; ++ni)
              so[ni << 4] = f2b(acc[mi][ni][rr]);
          } else {
            int t = slot_l[r] >> 2;
            float* oo = out + (size_t)t * DMODEL + nb0 + wn + (lane & 15);
#pragma unroll
            for (int ni = 0; ni < 4; ++ni)
              atomicAdd(&oo[ni << 4], acc[mi][ni][rr]);
          }
        }
      }
    }
#undef LOADA_DN
#undef LOADB_RS
#undef WR_A
#undef CVTWR_B
#undef MFMA_RS
  }
}

extern "C" void kernel_launch(void* const* d_in, const int* in_sizes, int n_in,
                              void* d_out, int out_size, void* d_ws, size_t ws_size,
                              hipStream_t stream) {
  (void)in_sizes; (void)n_in;
  const float* x      = (const float*)d_in[0];
  const float* keys   = (const float*)d_in[1];
  const float* values = (const float*)d_in[2];
  const float* es     = (const float*)d_in[3];
  float* out = (float*)d_out;

  char* W = (char*)d_ws;
  int*   cnt       = (int*)W;                        // 128 B
  u16*   zeros     = (u16*)(W + 4 * 1024);           // 4 KB
  u32*   selpk     = (u32*)(W + 16 * 1024);          // 16 KB
  float* selval    = (float*)(W + 64 * 1024);        // 64 KB
  float* blockpart = (float*)(W + 128 * 1024);       // 64 KB f32 [512][32]
  int*   bucket    = (int*)(W + 512 * 1024);         // 512 KB
  float* esT4      = (float*)(W + 1280 * 1024);      // 128 KB f32 [256][32][4]

  bool big = ws_size >= (90ull << 20);

  k_esT<<<32, 256, 0, stream>>>(es, esT4);

  if (big) {
    u16* xb     = (u16*)(W + 2ull * 1024 * 1024);    // 8 MB  bf16 [4096][1024]
    u16* scores = (u16*)(W + 10ull * 1024 * 1024);   // 16 MB bf16 [16384][512]
    u16* kb     = (u16*)(W + 26ull * 1024 * 1024);   // 32 MB bf16 [32][512][1024]
    u16* vb     = (u16*)(W + 58ull * 1024 * 1024);   // 32 MB bf16 [32][1024][512]
    u16* stage  = kb;  // aliases kb: kb dead after k_up, stage written by k_down
    hipMemsetAsync(zeros, 0, 4096, stream);
    // route (512, first) ∥ keys-tr (4096) ∥ values-tr (4096) — round-11 proven
    k_mega1<<<512 + 4096 + 4096, 256, 0, stream>>>(
        x, esT4, selval, selpk, blockpart, xb, keys, values, kb, vb);
    k_cf<<<1, 1024, 0, stream>>>(selpk, cnt, bucket, blockpart,
                                 out + (size_t)out_size - 1);
    k_up<<<512, 256, 0, stream>>>(xb, kb, selval, cnt, bucket, zeros, scores);
    k_down<<<512, 256, 0, stream>>>(scores, vb, cnt, bucket, zeros, stage);
    k_final<<<TOKENS / 2, 256, 0, stream>>>(stage, out);
  } else {
    u16* scores = (u16*)(W + 2ull * 1024 * 1024);
    bool big50 = ws_size >= (50ull << 20);
    u16* stage = big50 ? (u16*)(W + 18ull * 1024 * 1024) : nullptr;
    if (!big50)
      hipMemsetAsync(d_out, 0, (size_t)out_size * sizeof(float), stream);
    k_mega1<<<512, 256, 0, stream>>>(
        x, esT4, selval, selpk, blockpart, nullptr, nullptr, nullptr, nullptr, nullptr);
    k_cf<<<1, 1024, 0, stream>>>(selpk, cnt, bucket, blockpart,
                                 out + (size_t)out_size - 1);
    k_up_rs<<<512, 256, 0, stream>>>(x, keys, selval, cnt, bucket, scores);
    k_down_rs<<<512, 256, 0, stream>>>(scores, values, cnt, bucket, stage, out);
    if (big50)
      k_final<<<TOKENS / 2, 256, 0, stream>>>(stage, out);
  }
}

// Round 16
// 147.823 us; speedup vs baseline: 1.3051x; 1.1207x over previous
//
#include <hip/hip_runtime.h>
#include <hip/hip_bf16.h>

typedef unsigned short u16;
typedef unsigned int u32;
typedef __attribute__((ext_vector_type(4))) float f32x4;
typedef __attribute__((ext_vector_type(8))) short bf16x8;

#define TOKENS 4096
#define DMODEL 1024
#define NEXP 32
#define ESIZE 512

// round-to-nearest-even f32 -> bf16 bits
__device__ __forceinline__ u16 f2b(float f) {
  union { float f; u32 u; } v; v.f = f;
  u32 u = v.u;
  return (u16)((u + 0x7fffu + ((u >> 16) & 1u)) >> 16);
}

// packed f32x2 -> bf16x2
__device__ __forceinline__ u32 pk2(float a, float b) {
  union { __hip_bfloat162 h; u32 u; } v;
  v.h = __float22bfloat162_rn(make_float2(a, b));
  return v.u;
}

__device__ __forceinline__ float blo(u32 w) { union { u32 u; float f; } v; v.u = w << 16; return v.f; }
__device__ __forceinline__ float bhi(u32 w) { union { u32 u; float f; } v; v.u = w & 0xffff0000u; return v.f; }

// async global->LDS, 16B per lane; LDS dest = wave-uniform base + lane*16
typedef __attribute__((address_space(1))) const void as1_void;
typedef __attribute__((address_space(3))) void as3_void;
__device__ __forceinline__ void gl16(const void* g, void* l) {
  __builtin_amdgcn_global_load_lds((as1_void*)g, (as3_void*)l, 16, 0, 0);
}

// stride-72 swizzled LDS addr (shorts) for fallback reg-staged tiles
__device__ __forceinline__ int swz(int row, int kk) {
  return row * 72 + ((((kk >> 3) ^ (row >> 2)) & 7) << 3) + (kk & 7);
}

// ---------------- es transpose: esT4[dblk][e][j] = es[e][4*dblk+j] ----------------
__global__ __launch_bounds__(256) void k_esT(const float* __restrict__ es,
                                             float* __restrict__ esT4)
{
  int tid = threadIdx.x;
  int dblk = (blockIdx.x << 3) + (tid >> 5);
  int e = tid & 31;
  float4 v = *(const float4*)(es + (size_t)e * DMODEL + (dblk << 2));
  *((float4*)esT4 + (size_t)dblk * 32 + e) = v;
}

// ---------------- transpose-convert (round-11 proven): one 64x64 tile per block ----
// One tile per block keeps the 16 cy-chunks of each output row in concurrently-
// resident blocks -> full L2 line merging (WRITE_SIZE stays at compulsory).
__device__ __forceinline__ void tr_tile(const float* __restrict__ src,
                                        u16* __restrict__ dst, int R, int C,
                                        int cx, int cy, int e, int t, float* smemf)
{
  float (*tile)[68] = (float(*)[68])smemf;   // 64*68*4 = 17408 B
  int r0 = cy << 6, c0 = cx << 6;
  int rr = t >> 2, cb = (t & 3) << 4;
  const float* sp = src + ((size_t)e * R + r0 + rr) * C + c0 + cb;
#pragma unroll
  for (int j = 0; j < 4; ++j)
    *(float4*)&tile[rr][cb + (j << 2)] = *(const float4*)(sp + (j << 2));
  __syncthreads();
  int wr = t >> 2, wb = (t & 3) << 4;
  u32 q[8];
#pragma unroll
  for (int j = 0; j < 8; ++j)
    q[j] = pk2(tile[wb + (j << 1)][wr], tile[wb + (j << 1) + 1][wr]);
  u16* dp = dst + ((size_t)e * C + c0 + wr) * R + r0 + wb;
  *(uint4*)dp = make_uint4(q[0], q[1], q[2], q[3]);
  *(uint4*)(dp + 8) = make_uint4(q[4], q[5], q[6], q[7]);
}

// ---------------- mega1: route (0..511) ∥ keys-tr (512..4607) ∥ values-tr ------
__global__ __launch_bounds__(256) void k_mega1(
    const float* __restrict__ x, const float* __restrict__ esT4,
    float* __restrict__ selval, u32* __restrict__ selpk,
    float* __restrict__ blockpart, u16* __restrict__ xb,
    const float* __restrict__ keys, const float* __restrict__ values,
    u16* __restrict__ kb, u16* __restrict__ vb)
{
  __shared__ __align__(16) float smem[4352];   // 17408 B union
  int bid = blockIdx.x;
  int tid = threadIdx.x;

  if (bid >= 512 + 4096) {          // values-tr
    int i = bid - (512 + 4096);
    tr_tile(values, vb, ESIZE, DMODEL, i & 15, (i >> 4) & 7, i >> 7, tid, smem);
    return;
  }
  if (bid >= 512) {                 // keys-tr
    int i = bid - 512;
    tr_tile(keys, kb, DMODEL, ESIZE, i & 7, (i >> 3) & 15, i >> 7, tid, smem);
    return;
  }

  // ---- routing: K-split across 4 waves, 8 tokens/block ----
  float (*part)[8][32] = (float(*)[8][32])smem;          // 4 KB
  float (*ps)[32] = (float(*)[32])(smem + 1024);         // 1 KB
  int w = tid >> 6, lane = tid & 63;
  int e = lane & 31, h = lane >> 5;
  int t0 = bid << 3;

  const float4* ev = (const float4*)esT4 + (size_t)((w << 6) + (h << 5)) * 32 + e;
  const float4* xv = (const float4*)x + ((size_t)t0 << 8) + (w << 6) + (h << 5);

  float acc[8];
#pragma unroll
  for (int tk = 0; tk < 8; ++tk) acc[tk] = 0.f;

#pragma unroll 2
  for (int i = 0; i < 32; ++i) {
    float4 b = ev[(size_t)i * 32];
#pragma unroll
    for (int tk = 0; tk < 8; ++tk) {
      float4 a = xv[(tk << 8) + i];
      acc[tk] += a.x * b.x + a.y * b.y + a.z * b.z + a.w * b.w;
    }
  }
#pragma unroll
  for (int tk = 0; tk < 8; ++tk) {
    float s = acc[tk] + __shfl_xor(acc[tk], 32);
    if (h == 0) part[w][tk][e] = s;
  }
  __syncthreads();

  int tk = tid >> 5, ge = tid & 31;
  {
    float r = part[0][tk][ge] + part[1][tk][ge] + part[2][tk][ge] + part[3][tk][ge];
    int t = t0 + tk;

    float m = r;
#pragma unroll
    for (int mk = 16; mk; mk >>= 1) m = fmaxf(m, __shfl_xor(m, mk));
    float sx = __expf(r - m);
#pragma unroll
    for (int mk = 16; mk; mk >>= 1) sx += __shfl_xor(sx, mk);
    ps[tk][ge] = __expf(r - (m + __logf(sx)));

    u32 packed = 0;
    float v = r;
#pragma unroll
    for (int it = 0; it < 4; ++it) {
      float bv = v; int bi = ge;
#pragma unroll
      for (int mk = 16; mk; mk >>= 1) {
        float ov = __shfl_xor(bv, mk); int oi = __shfl_xor(bi, mk);
        if (ov > bv || (ov == bv && oi < bi)) { bv = ov; bi = oi; }
      }
      packed |= (u32)bi << (8 * it);
      if (ge == it) selval[t * 4 + it] = 1.f / (1.f + __expf(-bv));
      if (ge == bi) v = -3.0e38f;
    }
    if (ge == 0) selpk[t] = packed;
  }
  __syncthreads();
  if (tid < 32) {
    float s = 0.f;
#pragma unroll
    for (int j = 0; j < 8; ++j) s += ps[j][tid];
    blockpart[bid * 32 + tid] = s;
  }

  // fused x -> bf16 for this block's 8 rows (coalesced)
  if (xb) {
    const float4* src = (const float4*)x + ((size_t)bid << 11);
    u16* dst = xb + ((size_t)bid << 13);
#pragma unroll
    for (int j = 0; j < 8; ++j) {
      int idx = (j << 8) + tid;
      float4 a = src[idx];
      *(uint2*)(dst + (idx << 2)) = make_uint2(pk2(a.x, a.y), pk2(a.z, a.w));
    }
  }
}

// ---------------- bucket build + entropy regularizer (merged, uniform barriers) ----
__global__ __launch_bounds__(1024) void k_cf(
    const u32* __restrict__ selpk, int* __restrict__ cnt, int* __restrict__ bucket,
    const float* __restrict__ blockpart, float* __restrict__ out_reg)
{
  __shared__ int cl[32];
  __shared__ float pf[32][33];
  int tid = threadIdx.x;
  if (tid < 32) cl[tid] = 0;
  __syncthreads();
  int ex[16], pos[16];
#pragma unroll
  for (int j = 0; j < 4; ++j) {
    int t = tid + (j << 10);
    u32 pk = selpk[t];
#pragma unroll
    for (int h = 0; h < 4; ++h) {
      int e = (pk >> (8 * h)) & 0xff;
      ex[j * 4 + h] = e;
      pos[j * 4 + h] = atomicAdd(&cl[e], 1);
    }
  }
#pragma unroll
  for (int j = 0; j < 4; ++j) {
    int t = tid + (j << 10);
#pragma unroll
    for (int h = 0; h < 4; ++h)
      bucket[ex[j * 4 + h] * TOKENS + pos[j * 4 + h]] = (t << 2) | h;
  }
  __syncthreads();
  if (tid < 32) cnt[tid] = cl[tid];

  // fin: colsum over 512 blockparts
  int e = tid & 31, c = tid >> 5;
  float s = 0.f;
  for (int b = c; b < 512; b += 32) s += blockpart[b * 32 + e];
  pf[c][e] = s;
  __syncthreads();
  if (tid < 32) {
    float S = 0.f;
#pragma unroll
    for (int i = 0; i < 32; ++i) S += pf[i][tid];
    float Pm = S * (1.0f / TOKENS);
    float rp = __logf(Pm) * Pm;
#pragma unroll
    for (int mk = 16; mk; mk >>= 1) rp += __shfl_xor(rp, mk);
    if (tid == 0) *out_reg = rp;
  }
}

// ======== fast GEMMs (round-9/11 proven): BK=64, global_load_lds staging,
// XOR-granule swizzle, 2-deep counted-vmcnt pipeline ========
#define GEMM_MACROS                                                                          \
  int wm = (w >> 1) << 6, wn = (w & 1) << 6;                                                 \
  int w32 = w << 5;                                                                          \
  int lg16 = (((l & 7) ^ (l >> 3)) << 4);

#define STAGE(BUF, K0) do {                                                                  \
  _Pragma("unroll") for (int i_ = 0; i_ < 4; ++i_)                                           \
    gl16(gA[i_] + ((K0) << 1), (void*)&Ab[BUF][(((w << 2) + i_) << 9)]);                     \
  _Pragma("unroll") for (int i_ = 0; i_ < 4; ++i_)                                           \
    gl16(gB[i_] + ((K0) << 1), (void*)&Bb[BUF][(((w << 2) + i_) << 9)]);                     \
} while (0)

#define COMPUTE(CUR) do {                                                                    \
  _Pragma("unroll") for (int kh_ = 0; kh_ < 2; ++kh_) {                                      \
    bf16x8 af_[4], bf_[4];                                                                   \
    int gg_ = (kh_ << 2) + (l >> 4);                                                         \
    _Pragma("unroll") for (int mi_ = 0; mi_ < 4; ++mi_) {                                    \
      int row_ = wm + (mi_ << 4) + (l & 15);                                                 \
      af_[mi_] = *(const bf16x8*)&Ab[CUR][(row_ << 6) + ((gg_ ^ (row_ & 7)) << 3)];          \
    }                                                                                        \
    _Pragma("unroll") for (int ni_ = 0; ni_ < 4; ++ni_) {                                    \
      int row_ = wn + (ni_ << 4) + (l & 15);                                                 \
      bf_[ni_] = *(const bf16x8*)&Bb[CUR][(row_ << 6) + ((gg_ ^ (row_ & 7)) << 3)];          \
    }                                                                                        \
    _Pragma("unroll") for (int mi_ = 0; mi_ < 4; ++mi_)                                      \
      _Pragma("unroll") for (int ni_ = 0; ni_ < 4; ++ni_)                                    \
        acc[mi_][ni_] = __builtin_amdgcn_mfma_f32_16x16x32_bf16(af_[mi_], bf_[ni_],          \
                                                                acc[mi_][ni_], 0, 0, 0);     \
  }                                                                                          \
} while (0)

// counted-vmcnt K-loop over NT tiles of 64
#define KLOOP(NT) do {                                                                       \
  STAGE(0, 0);                                                                               \
  STAGE(1, 64);                                                                              \
  _Pragma("unroll 1")                                                                        \
  for (int t_ = 0; t_ < (NT); ++t_) {                                                        \
    int cur_ = t_ & 1;                                                                       \
    if (t_ + 1 < (NT)) { asm volatile("s_waitcnt vmcnt(8)" ::: "memory"); }                  \
    else               { asm volatile("s_waitcnt vmcnt(0)" ::: "memory"); }                  \
    asm volatile("s_barrier" ::: "memory");                                                  \
    COMPUTE(cur_);                                                                           \
    asm volatile("s_barrier" ::: "memory");                                                  \
    if (t_ + 2 < (NT)) STAGE(cur_, (t_ + 2) << 6);                                           \
  }                                                                                          \
} while (0)

// XCD-affine decode: bid = ((e>>3)*16 + sub)*8 + (e&7)
#define XCD_DECODE(SUB_NS_BITS)                                                              \
  int bid = blockIdx.x;                                                                      \
  int q_ = bid >> 3, sub_ = q_ & 15;                                                         \
  int e = ((q_ >> 4) << 3) | (bid & 7);                                                      \
  int ns = sub_ & ((1 << (SUB_NS_BITS)) - 1);                                                \
  int mz = sub_ >> (SUB_NS_BITS);

// ---------------- up-projection: scores[slot] = relu(xb[t] @ kb[e]^T) * gate ----------------
__global__ __launch_bounds__(256, 2) void k_up(
    const u16* __restrict__ xb, const u16* __restrict__ kb,
    const float* __restrict__ selval, const int* __restrict__ cnt,
    const int* __restrict__ bucket, const u16* __restrict__ zeros,
    u16* __restrict__ scores)
{
  XCD_DECODE(2);                       // 4 ns x 4 mz
  int ne = cnt[e];
  if ((mz << 7) >= ne) return;
  int nb0 = ns << 7;
  int tid = threadIdx.x, l = tid & 63, w = tid >> 6;

  __shared__ __align__(16) u16 Ab[2][8192];
  __shared__ __align__(16) u16 Bb[2][8192];
  __shared__ int slot_l[128];
  __shared__ float gate_l[128];

  GEMM_MACROS;

  const char* gB[4];
#pragma unroll
  for (int i = 0; i < 4; ++i) {
    int n = nb0 + w32 + (i << 3) + (l >> 3);
    gB[i] = (const char*)(kb + ((size_t)e * ESIZE + n) * DMODEL) + lg16;
  }

  for (int mt = mz; (mt << 7) < ne; mt += 4) {
    int row0 = mt << 7;
    int rem = ne - row0; if (rem > 128) rem = 128;
    __syncthreads();
    if (tid < 128) {
      int slot = -1; float g = 0.f;
      if (tid < rem) { slot = bucket[e * TOKENS + row0 + tid]; g = selval[slot]; }
      slot_l[tid] = slot; gate_l[tid] = g;
    }
    __syncthreads();

    const char* gA[4];
#pragma unroll
    for (int i = 0; i < 4; ++i) {
      int s = slot_l[w32 + (i << 3) + (l >> 3)];
      gA[i] = ((s >= 0) ? (const char*)(xb + (size_t)(s >> 2) * DMODEL)
                        : (const char*)zeros) + lg16;
    }

    f32x4 acc[4][4];
#pragma unroll
    for (int i = 0; i < 4; ++i)
#pragma unroll
      for (int j = 0; j < 4; ++j) acc[i][j] = (f32x4){0.f, 0.f, 0.f, 0.f};

    KLOOP(16);

#pragma unroll
    for (int mi = 0; mi < 4; ++mi) {
      int rbase = wm + (mi << 4) + ((l >> 4) << 2);
#pragma unroll
      for (int rr = 0; rr < 4; ++rr) {
        int r = rbase + rr;
        if (r < rem) {
          float g = gate_l[r];
          u16* so = scores + (size_t)slot_l[r] * ESIZE + nb0 + wn + (l & 15);
#pragma unroll
          for (int ni = 0; ni < 4; ++ni)
            so[ni << 4] = f2b(fmaxf(acc[mi][ni][rr], 0.f) * g);
        }
      }
    }
  }
}

// ---------------- down-projection: stage[slot] = scores[slot] @ vb[e]^T ----------------
__global__ __launch_bounds__(256, 2) void k_down(
    const u16* __restrict__ scores, const u16* __restrict__ vb,
    const int* __restrict__ cnt, const int* __restrict__ bucket,
    const u16* __restrict__ zeros, u16* __restrict__ stage)
{
  XCD_DECODE(3);                       // 8 ns x 2 mz
  int ne = cnt[e];
  if ((mz << 7) >= ne) return;
  int nb0 = ns << 7;
  int tid = threadIdx.x, l = tid & 63, w = tid >> 6;

  __shared__ __align__(16) u16 Ab[2][8192];
  __shared__ __align__(16) u16 Bb[2][8192];
  __shared__ int slot_l[128];

  GEMM_MACROS;

  const char* gB[4];
#pragma unroll
  for (int i = 0; i < 4; ++i) {
    int n = nb0 + w32 + (i << 3) + (l >> 3);
    gB[i] = (const char*)(vb + ((size_t)e * DMODEL + n) * ESIZE) + lg16;
  }

  for (int mt = mz; (mt << 7) < ne; mt += 2) {
    int row0 = mt << 7;
    int rem = ne - row0; if (rem > 128) rem = 128;
    __syncthreads();
    if (tid < 128) {
      int slot = -1;
      if (tid < rem) slot = bucket[e * TOKENS + row0 + tid];
      slot_l[tid] = slot;
    }
    __syncthreads();

    const char* gA[4];
#pragma unroll
    for (int i = 0; i < 4; ++i) {
      int s = slot_l[w32 + (i << 3) + (l >> 3)];
      gA[i] = ((s >= 0) ? (const char*)(scores + (size_t)s * ESIZE)
                        : (const char*)zeros) + lg16;
    }

    f32x4 acc[4][4];
#pragma unroll
    for (int i = 0; i < 4; ++i)
#pragma unroll
      for (int j = 0; j < 4; ++j) acc[i][j] = (f32x4){0.f, 0.f, 0.f, 0.f};

    KLOOP(8);

#pragma unroll
    for (int mi = 0; mi < 4; ++mi) {
      int rbase = wm + (mi << 4) + ((l >> 4) << 2);
#pragma unroll
      for (int rr = 0; rr < 4; ++rr) {
        int r = rbase + rr;
        if (r < rem) {
          u16* so = stage + (size_t)slot_l[r] * DMODEL + nb0 + wn + (l & 15);
#pragma unroll
          for (int ni = 0; ni < 4; ++ni)
            so[ni << 4] = f2b(acc[mi][ni][rr]);
        }
      }
    }
  }
}

// ---------------- final: out[t] = sum_h stage[t*4+h] ----------------
__global__ __launch_bounds__(256) void k_final(const u16* __restrict__ stage,
                                               float* __restrict__ out)
{
  int tid = threadIdx.x;
  int t = (blockIdx.x << 1) + (tid >> 7);
  int d0 = (tid & 127) << 3;
  const u16* r0 = stage + ((size_t)t << 12) + d0;
  uint4 a0 = *(const uint4*)(r0);
  uint4 a1 = *(const uint4*)(r0 + 1024);
  uint4 a2 = *(const uint4*)(r0 + 2048);
  uint4 a3 = *(const uint4*)(r0 + 3072);
  float4 lo4, hi4;
  lo4.x = blo(a0.x) + blo(a1.x) + blo(a2.x) + blo(a3.x);
  lo4.y = bhi(a0.x) + bhi(a1.x) + bhi(a2.x) + bhi(a3.x);
  lo4.z = blo(a0.y) + blo(a1.y) + blo(a2.y) + blo(a3.y);
  lo4.w = bhi(a0.y) + bhi(a1.y) + bhi(a2.y) + bhi(a3.y);
  hi4.x = blo(a0.z) + blo(a1.z) + blo(a2.z) + blo(a3.z);
  hi4.y = bhi(a0.z) + bhi(a1.z) + bhi(a2.z) + bhi(a3.z);
  hi4.z = blo(a0.w) + blo(a1.w) + blo(a2.w) + blo(a3.w);
  hi4.w = bhi(a0.w) + bhi(a1.w) + bhi(a2.w) + bhi(a3.w);
  float* o = out + (size_t)t * DMODEL + d0;
  *(float4*)o = lo4;
  *(float4*)(o + 4) = hi4;
}

// ================= fallback (reg-staged) kernels, used if ws too small =================
__global__ __launch_bounds__(256, 2) void k_up_rs(
    const float* __restrict__ x, const float* __restrict__ keys,
    const float* __restrict__ selval, const int* __restrict__ cnt,
    const int* __restrict__ bucket, u16* __restrict__ scores)
{
  int bid = blockIdx.x;
  int pair = bid & 127, mz = bid >> 7;
  int e = pair >> 2, ns = pair & 3;
  int ne = cnt[e];
  if ((mz << 7) >= ne) return;
  int nb0 = ns << 7;
  int tid = threadIdx.x;

  __shared__ __align__(16) u16 Abuf[2][128 * 72];
  __shared__ __align__(16) u16 Bbuf[2][128 * 72];
  __shared__ int slot_l[128];
  __shared__ float gate_l[128];

  const float* Kb = keys + (size_t)e * (DMODEL * ESIZE) + nb0;
  int arow = tid >> 1, ac0 = (tid & 1) << 5;
  int bn = tid & 31, bk0 = (tid >> 5) << 3;
  int lane = tid & 63, w = tid >> 6;
  int wm = (w >> 1) << 6, wn = (w & 1) << 6;

  for (int mt = mz; (mt << 7) < ne; mt += 4) {
    int row0 = mt << 7;
    int rem = ne - row0; if (rem > 128) rem = 128;
    __syncthreads();
    if (tid < 128) {
      int slot = -1; float g = 0.f;
      if (tid < rem) { slot = bucket[e * TOKENS + row0 + tid]; g = selval[slot]; }
      slot_l[tid] = slot; gate_l[tid] = g;
    }
    __syncthreads();

    int aslot = slot_l[arow];
    const float* xr = (aslot >= 0) ? (x + (size_t)(aslot >> 2) * DMODEL + ac0) : nullptr;
    const float* bp = Kb + (size_t)bk0 * ESIZE + (bn << 2);

    f32x4 acc[4][4];
#pragma unroll
    for (int i = 0; i < 4; ++i)
#pragma unroll
      for (int j = 0; j < 4; ++j) acc[i][j] = (f32x4){0.f, 0.f, 0.f, 0.f};

    float4 ar[8], br[8];
#define LOADA_UP(K) do { if (xr) { const float4* p_ = (const float4*)(xr + (K)); \
    _Pragma("unroll") for (int i_ = 0; i_ < 8; ++i_) ar[i_] = p_[i_]; } \
    else { _Pragma("unroll") for (int i_ = 0; i_ < 8; ++i_) ar[i_] = make_float4(0.f,0.f,0.f,0.f); } } while (0)
#define LOADB_RS(K, LDB) do { const float* q_ = bp + (size_t)(K) * (LDB); \
    _Pragma("unroll") for (int r_ = 0; r_ < 8; ++r_) br[r_] = *(const float4*)(q_ + (size_t)r_ * (LDB)); } while (0)
#define CVTWR_A(NB) do { _Pragma("unroll") for (int g_ = 0; g_ < 4; ++g_) { \
    u32 q0_ = pk2(ar[2*g_].x, ar[2*g_].y),   q1_ = pk2(ar[2*g_].z, ar[2*g_].w); \
    u32 q2_ = pk2(ar[2*g_+1].x, ar[2*g_+1].y), q3_ = pk2(ar[2*g_+1].z, ar[2*g_+1].w); \
    *(uint4*)&Abuf[NB][swz(arow, ac0 + 8*g_)] = make_uint4(q0_,q1_,q2_,q3_); } } while (0)
#define CVTWR_B(NB) do { \
    { u32 q0_=pk2(br[0].x,br[1].x),q1_=pk2(br[2].x,br[3].x),q2_=pk2(br[4].x,br[5].x),q3_=pk2(br[6].x,br[7].x); \
      *(uint4*)&Bbuf[NB][swz((bn<<2)+0, bk0)] = make_uint4(q0_,q1_,q2_,q3_); } \
    { u32 q0_=pk2(br[0].y,br[1].y),q1_=pk2(br[2].y,br[3].y),q2_=pk2(br[4].y,br[5].y),q3_=pk2(br[6].y,br[7].y); \
      *(uint4*)&Bbuf[NB][swz((bn<<2)+1, bk0)] = make_uint4(q0_,q1_,q2_,q3_); } \
    { u32 q0_=pk2(br[0].z,br[1].z),q1_=pk2(br[2].z,br[3].z),q2_=pk2(br[4].z,br[5].z),q3_=pk2(br[6].z,br[7].z); \
      *(uint4*)&Bbuf[NB][swz((bn<<2)+2, bk0)] = make_uint4(q0_,q1_,q2_,q3_); } \
    { u32 q0_=pk2(br[0].w,br[1].w),q1_=pk2(br[2].w,br[3].w),q2_=pk2(br[4].w,br[5].w),q3_=pk2(br[6].w,br[7].w); \
      *(uint4*)&Bbuf[NB][swz((bn<<2)+3, bk0)] = make_uint4(q0_,q1_,q2_,q3_); } } while (0)
#define MFMA_RS(CUR) do { _Pragma("unroll") for (int kh_ = 0; kh_ < 2; ++kh_) { \
    int kk_ = (kh_ << 5) | ((lane >> 4) << 3); \
    bf16x8 af_[4], bf_[4]; \
    _Pragma("unroll") for (int mi_ = 0; mi_ < 4; ++mi_) \
      af_[mi_] = *(const bf16x8*)&Abuf[CUR][swz(wm + (mi_ << 4) + (lane & 15), kk_)]; \
    _Pragma("unroll") for (int ni_ = 0; ni_ < 4; ++ni_) \
      bf_[ni_] = *(const bf16x8*)&Bbuf[CUR][swz(wn + (ni_ << 4) + (lane & 15), kk_)]; \
    _Pragma("unroll") for (int mi_ = 0; mi_ < 4; ++mi_) \
      _Pragma("unroll") for (int ni_ = 0; ni_ < 4; ++ni_) \
        acc[mi_][ni_] = __builtin_amdgcn_mfma_f32_16x16x32_bf16(af_[mi_], bf_[ni_], acc[mi_][ni_], 0, 0, 0); \
  } } while (0)

    LOADA_UP(0); LOADB_RS(0, ESIZE);
    CVTWR_A(0); CVTWR_B(0);
    __syncthreads();
    int cur = 0;
    for (int k0 = 0; k0 < DMODEL; k0 += 64) {
      bool late = (k0 + 64 >= DMODEL);
      if (!late) { LOADA_UP(k0 + 64); LOADB_RS(k0 + 64, ESIZE); }
      MFMA_RS(cur);
      if (!late) { CVTWR_A(cur ^ 1); CVTWR_B(cur ^ 1); }
      __syncthreads();
      cur ^= 1;
    }

#pragma unroll
    for (int mi = 0; mi < 4; ++mi) {
      int rbase = wm + (mi << 4) + ((lane >> 4) << 2);
#pragma unroll
      for (int rr = 0; rr < 4; ++rr) {
        int r = rbase + rr;
        if (r < rem) {
          float g = gate_l[r];
          u16* so = scores + (size_t)slot_l[r] * ESIZE + nb0 + wn + (lane & 15);
#pragma unroll
          for (int ni = 0; ni < 4; ++ni)
            so[ni << 4] = f2b(fmaxf(acc[mi][ni][rr], 0.f) * g);
        }
      }
    }
#undef LOADA_UP
#undef LOADB_RS
#undef CVTWR_A
#undef CVTWR_B
#undef MFMA_RS
  }
}

__global__ __launch_bounds__(256, 2) void k_down_rs(
    const u16* __restrict__ scores, const float* __restrict__ values,
    const int* __restrict__ cnt, const int* __restrict__ bucket,
    u16* __restrict__ stage, float* __restrict__ out)
{
  int bid = blockIdx.x;
  int pair = bid & 255, mz = bid >> 8;
  int e = pair >> 3, ns = pair & 7;
  int ne = cnt[e];
  if ((mz << 7) >= ne) return;
  int nb0 = ns << 7;
  int tid = threadIdx.x;

  __shared__ __align__(16) u16 Abuf[2][128 * 72];
  __shared__ __align__(16) u16 Bbuf[2][128 * 72];
  __shared__ int slot_l[128];

  const float* Vb = values + (size_t)e * (ESIZE * DMODEL) + nb0;
  int arow = tid >> 1, ac0 = (tid & 1) << 5;
  int bn = tid & 31, bk0 = (tid >> 5) << 3;
  int lane = tid & 63, w = tid >> 6;
  int wm = (w >> 1) << 6, wn = (w & 1) << 6;

  for (int mt = mz; (mt << 7) < ne; mt += 2) {
    int row0 = mt << 7;
    int rem = ne - row0; if (rem > 128) rem = 128;
    __syncthreads();
    if (tid < 128) {
      int slot = -1;
      if (tid < rem) slot = bucket[e * TOKENS + row0 + tid];
      slot_l[tid] = slot;
    }
    __syncthreads();

    int aslot = slot_l[arow];
    const u16* sr = (aslot >= 0) ? (scores + (size_t)aslot * ESIZE + ac0) : nullptr;
    const float* bp = Vb + (size_t)bk0 * DMODEL + (bn << 2);

    f32x4 acc[4][4];
#pragma unroll
    for (int i = 0; i < 4; ++i)
#pragma unroll
      for (int j = 0; j < 4; ++j) acc[i][j] = (f32x4){0.f, 0.f, 0.f, 0.f};

    uint4 a4[4]; float4 br[8];
#define LOADA_DN(K) do { if (sr) { const uint4* p_ = (const uint4*)(sr + (K)); \
    _Pragma("unroll") for (int i_ = 0; i_ < 4; ++i_) a4[i_] = p_[i_]; } \
    else { _Pragma("unroll") for (int i_ = 0; i_ < 4; ++i_) a4[i_] = make_uint4(0,0,0,0); } } while (0)
#define LOADB_RS(K, LDB) do { const float* q_ = bp + (size_t)(K) * (LDB); \
    _Pragma("unroll") for (int r_ = 0; r_ < 8; ++r_) br[r_] = *(const float4*)(q_ + (size_t)r_ * (LDB)); } while (0)
#define WR_A(NB) do { _Pragma("unroll") for (int g_ = 0; g_ < 4; ++g_) \
    *(uint4*)&Abuf[NB][swz(arow, ac0 + 8*g_)] = a4[g_]; } while (0)
#define CVTWR_B(NB) do { \
    { u32 q0_=pk2(br[0].x,br[1].x),q1_=pk2(br[2].x,br[3].x),q2_=pk2(br[4].x,br[5].x),q3_=pk2(br[6].x,br[7].x); \
      *(uint4*)&Bbuf[NB][swz((bn<<2)+0, bk0)] = make_uint4(q0_,q1_,q2_,q3_); } \
    { u32 q0_=pk2(br[0].y,br[1].y),q1_=pk2(br[2].y,br[3].y),q2_=pk2(br[4].y,br[5].y),q3_=pk2(br[6].y,br[7].y); \
      *(uint4*)&Bbuf[NB][swz((bn<<2)+1, bk0)] = make_uint4(q0_,q1_,q2_,q3_); } \
    { u32 q0_=pk2(br[0].z,br[1].z),q1_=pk2(br[2].z,br[3].z),q2_=pk2(br[4].z,br[5].z),q3_=pk2(br[6].z,br[7].z); \
      *(uint4*)&Bbuf[NB][swz((bn<<2)+2, bk0)] = make_uint4(q0_,q1_,q2_,q3_); } \
    { u32 q0_=pk2(br[0].w,br[1].w),q1_=pk2(br[2].w,br[3].w),q2_=pk2(br[4].w,br[5].w),q3_=pk2(br[6].w,br[7].w); \
      *(uint4*)&Bbuf[NB][swz((bn<<2)+3, bk0)] = make_uint4(q0_,q1_,q2_,q3_); } } while (0)
#define MFMA_RS(CUR) do { _Pragma("unroll") for (int kh_ = 0; kh_ < 2; ++kh_) { \
    int kk_ = (kh_ << 5) | ((lane >> 4) << 3); \
    bf16x8 af_[4], bf_[4]; \
    _Pragma("unroll") for (int mi_ = 0; mi_ < 4; ++mi_) \
      af_[mi_] = *(const bf16x8*)&Abuf[CUR][swz(wm + (mi_ << 4) + (lane & 15), kk_)]; \
    _Pragma("unroll") for (int ni_ = 0; ni_ < 4; ++ni_) \
      bf_[ni_] = *(const bf16x8*)&Bbuf[CUR][swz(wn + (ni_ << 4) + (lane & 15), kk_)]; \
    _Pragma("unroll") for (int mi_ = 0; mi_ < 4; ++mi_) \
      _Pragma("unroll") for (int ni_ = 0; ni_ < 4; ++ni_) \
        acc[mi_][ni_] = __builtin_amdgcn_mfma_f32_16x16x32_bf16(af_[mi_], bf_[ni_], acc[mi_][ni_], 0, 0, 0); \
  } } while (0)

    LOADA_DN(0); LOADB_RS(0, DMODEL);
    WR_A(0); CVTWR_B(0);
    __syncthreads();
    int cur = 0;
    for (int k0 = 0; k0 < ESIZE; k0 += 64) {
      bool late = (k0 + 64 >= ESIZE);
      if (!late) { LOADA_DN(k0 + 64); LOADB_RS(k0 + 64, DMODEL); }
      MFMA_RS(cur);
      if (!late) { WR_A(cur ^ 1); CVTWR_B(cur ^ 1); }
      __syncthreads();
      cur ^= 1;
    }

#pragma unroll
    for (int mi = 0; mi < 4; ++mi) {
      int rbase = wm + (mi << 4) + ((lane >> 4) << 2);
#pragma unroll
      for (int rr = 0; rr < 4; ++rr) {
        int r = rbase + rr;
        if (r < rem) {
          if (stage) {
            u16* so = stage + (size_t)slot_l[r] * DMODEL + nb0 + wn + (lane & 15);
#pragma unroll
            for (int ni = 0; ni < 4; ++ni)
              so[ni << 4] = f2b(acc[mi][ni][rr]);
          } else {
            int t = slot_l[r] >> 2;
            float* oo = out + (size_t)t * DMODEL + nb0 + wn + (lane & 15);
#pragma unroll
            for (int ni = 0; ni < 4; ++ni)
              atomicAdd(&oo[ni << 4], acc[mi][ni][rr]);
          }
        }
      }
    }
#undef LOADA_DN
#undef LOADB_RS
#undef WR_A
#undef CVTWR_B
#undef MFMA_RS
  }
}

extern "C" void kernel_launch(void* const* d_in, const int* in_sizes, int n_in,
                              void* d_out, int out_size, void* d_ws, size_t ws_size,
                              hipStream_t stream) {
  (void)in_sizes; (void)n_in;
  const float* x      = (const float*)d_in[0];
  const float* keys   = (const float*)d_in[1];
  const float* values = (const float*)d_in[2];
  const float* es     = (const float*)d_in[3];
  float* out = (float*)d_out;

  char* W = (char*)d_ws;
  int*   cnt       = (int*)W;                        // 128 B
  u16*   zeros     = (u16*)(W + 4 * 1024);           // 4 KB
  u32*   selpk     = (u32*)(W + 16 * 1024);          // 16 KB
  float* selval    = (float*)(W + 64 * 1024);        // 64 KB
  float* blockpart = (float*)(W + 128 * 1024);       // 64 KB f32 [512][32]
  int*   bucket    = (int*)(W + 512 * 1024);         // 512 KB
  float* esT4      = (float*)(W + 1280 * 1024);      // 128 KB f32 [256][32][4]

  bool big = ws_size >= (90ull << 20);

  k_esT<<<32, 256, 0, stream>>>(es, esT4);

  if (big) {
    u16* xb     = (u16*)(W + 2ull * 1024 * 1024);    // 8 MB  bf16 [4096][1024]
    u16* scores = (u16*)(W + 10ull * 1024 * 1024);   // 16 MB bf16 [16384][512]
    u16* kb     = (u16*)(W + 26ull * 1024 * 1024);   // 32 MB bf16 [32][512][1024]
    u16* vb     = (u16*)(W + 58ull * 1024 * 1024);   // 32 MB bf16 [32][1024][512]
    u16* stage  = kb;  // aliases kb: kb dead after k_up, stage written by k_down
    hipMemsetAsync(zeros, 0, 4096, stream);
    // route (512, first) ∥ keys-tr (4096) ∥ values-tr (4096) — round-11 proven
    k_mega1<<<512 + 4096 + 4096, 256, 0, stream>>>(
        x, esT4, selval, selpk, blockpart, xb, keys, values, kb, vb);
    k_cf<<<1, 1024, 0, stream>>>(selpk, cnt, bucket, blockpart,
                                 out + (size_t)out_size - 1);
    k_up<<<512, 256, 0, stream>>>(xb, kb, selval, cnt, bucket, zeros, scores);
    k_down<<<512, 256, 0, stream>>>(scores, vb, cnt, bucket, zeros, stage);
    k_final<<<TOKENS / 2, 256, 0, stream>>>(stage, out);
  } else {
    u16* scores = (u16*)(W + 2ull * 1024 * 1024);
    bool big50 = ws_size >= (50ull << 20);
    u16* stage = big50 ? (u16*)(W + 18ull * 1024 * 1024) : nullptr;
    if (!big50)
      hipMemsetAsync(d_out, 0, (size_t)out_size * sizeof(float), stream);
    k_mega1<<<512, 256, 0, stream>>>(
        x, esT4, selval, selpk, blockpart, nullptr, nullptr, nullptr, nullptr, nullptr);
    k_cf<<<1, 1024, 0, stream>>>(selpk, cnt, bucket, blockpart,
                                 out + (size_t)out_size - 1);
    k_up_rs<<<512, 256, 0, stream>>>(x, keys, selval, cnt, bucket, scores);
    k_down_rs<<<512, 256, 0, stream>>>(scores, values, cnt, bucket, stage, out);
    if (big50)
      k_final<<<TOKENS / 2, 256, 0, stream>>>(stage, out);
  }
}